// Round 9
// baseline (371.603 us; speedup 1.0000x reference)
//
#include <hip/hip_runtime.h>
#include <hip/hip_bf16.h>
#include <math.h>

#define NN 100000
#define NE 1600000

constexpr float EPS = 1e-8f;
constexpr float LN_EPS = 1e-5f;

typedef short bf16x8 __attribute__((ext_vector_type(8)));
typedef float f32x4 __attribute__((ext_vector_type(4)));

__device__ __forceinline__ float rcp_fast(float v) {
    return __builtin_amdgcn_rcpf(v);
}
__device__ __forceinline__ float silu_f(float v) {
    return v * rcp_fast(1.0f + __expf(-v));
}
__device__ __forceinline__ short f2bf_hw(float v) {
    union { __hip_bfloat16 b; short s; } u;
    u.b = __float2bfloat16(v);
    return u.s;
}
__device__ __forceinline__ unsigned int pk2_hw(float lo, float hi) {
    union { __hip_bfloat162 b2; unsigned int u; } u;
    u.b2 = __float22bfloat162_rn(make_float2(lo, hi));
    return u.u;
}
__device__ __forceinline__ float bf2f(unsigned short s) {
    return __uint_as_float(((unsigned int)s) << 16);
}

// ---------------- fused prep: bf16 h + frag-packed weights + count+rank ------
// frag order: elem ((c*4+nt)*64 + l)*8 + j  ==  W[k = c*32+(l>>4)*8+j][n]
// OUTPUT-CHANNEL PERM: n = (l&15)*4 + nt

#define HB_BLOCKS 6250      // NN*64/4/256
#define PW_BLOCKS 120
#define CNT_BLOCKS 6250     // NE/256

__global__ void prep_count_kernel(const float* __restrict__ h,
                            const float* __restrict__ W1, const float* __restrict__ W2,
                            const float* __restrict__ Wc1,
                            const float* __restrict__ Wn1, const float* __restrict__ Wn2,
                            const int* __restrict__ ei,
                            unsigned short* __restrict__ hbf,
                            unsigned short* __restrict__ W1p, unsigned short* __restrict__ W2p,
                            unsigned short* __restrict__ Wc1p,
                            unsigned short* __restrict__ Wn1p, unsigned short* __restrict__ Wn2p,
                            int* __restrict__ counts, int* __restrict__ rank)
{
    const int b = blockIdx.x;
    if (b < HB_BLOCKS) {
        const int i = b * 256 + threadIdx.x;     // 4 elems each
        const float4 v = ((const float4*)h)[i];
        uint2 u; u.x = pk2_hw(v.x, v.y); u.y = pk2_hw(v.z, v.w);
        ((uint2*)hbf)[i] = u;
        return;
    }
    if (b < HB_BLOCKS + PW_BLOCKS) {
        const int idx = (b - HB_BLOCKS) * 256 + threadIdx.x;
        if (idx < 10240) {                           // W1: K=160 (145 real)
            const int j = idx & 7, l = (idx >> 3) & 63, nt = (idx >> 9) & 3, c = idx >> 11;
            const int k = c * 32 + (l >> 4) * 8 + j, n = (l & 15) * 4 + nt;
            W1p[idx] = (k < 145) ? (unsigned short)f2bf_hw(W1[k * 64 + n]) : (unsigned short)0;
        } else if (idx < 14336) {                    // W2: K=64
            const int t = idx - 10240;
            const int j = t & 7, l = (t >> 3) & 63, nt = (t >> 9) & 3, c = t >> 11;
            W2p[t] = (unsigned short)f2bf_hw(W2[(c * 32 + (l >> 4) * 8 + j) * 64 + (l & 15) * 4 + nt]);
        } else if (idx < 18432) {                    // Wc1: K=64
            const int t = idx - 14336;
            const int j = t & 7, l = (t >> 3) & 63, nt = (t >> 9) & 3, c = t >> 11;
            Wc1p[t] = (unsigned short)f2bf_hw(Wc1[(c * 32 + (l >> 4) * 8 + j) * 64 + (l & 15) * 4 + nt]);
        } else if (idx < 26624) {                    // Wn1: K=128
            const int t = idx - 18432;
            const int j = t & 7, l = (t >> 3) & 63, nt = (t >> 9) & 3, c = t >> 11;
            Wn1p[t] = (unsigned short)f2bf_hw(Wn1[(c * 32 + (l >> 4) * 8 + j) * 64 + (l & 15) * 4 + nt]);
        } else if (idx < 30720) {                    // Wn2: K=64
            const int t = idx - 26624;
            const int j = t & 7, l = (t >> 3) & 63, nt = (t >> 9) & 3, c = t >> 11;
            Wn2p[t] = (unsigned short)f2bf_hw(Wn2[(c * 32 + (l >> 4) * 8 + j) * 64 + (l & 15) * 4 + nt]);
        }
        return;
    }
    // count + rank in one atomic pass: the returned old value IS the rank
    const int e = (b - HB_BLOCKS - PW_BLOCKS) * 256 + threadIdx.x;
    if (e < NE) rank[e] = atomicAdd(&counts[ei[e]], 1);
}

// ---------------- CSR build (scan + fused atomic-free scatter) ----------------

#define SCAN_B 512
__global__ __launch_bounds__(SCAN_B) void scan1_kernel(const int* __restrict__ counts,
                                                       int* __restrict__ offs,
                                                       int* __restrict__ bsum) {
    __shared__ int s[SCAN_B];
    const int tid = threadIdx.x;
    const int idx = blockIdx.x * SCAN_B + tid;
    const int v = (idx < NN) ? counts[idx] : 0;
    s[tid] = v;
    __syncthreads();
    for (int off = 1; off < SCAN_B; off <<= 1) {
        const int t = (tid >= off) ? s[tid - off] : 0;
        __syncthreads();
        s[tid] += t;
        __syncthreads();
    }
    if (idx < NN) offs[idx] = s[tid] - v;         // block-local exclusive
    if (tid == SCAN_B - 1) bsum[blockIdx.x] = s[tid];
}

__global__ __launch_bounds__(SCAN_B) void scan2_kernel(int* __restrict__ bsum, int nblk) {
    __shared__ int s[SCAN_B];
    const int tid = threadIdx.x;
    const int v = (tid < nblk) ? bsum[tid] : 0;
    s[tid] = v;
    __syncthreads();
    for (int off = 1; off < SCAN_B; off <<= 1) {
        const int t = (tid >= off) ? s[tid - off] : 0;
        __syncthreads();
        s[tid] += t;
        __syncthreads();
    }
    if (tid < nblk) bsum[tid] = s[tid] - v;       // exclusive
}

// scatter with fused block-sum add (no scan3 pass)
__global__ void scatter_kernel(const int* __restrict__ ei, const int* __restrict__ offs,
                               const int* __restrict__ bsum, const int* __restrict__ rank,
                               int4* __restrict__ quads) {
    const int e = blockIdx.x * 256 + threadIdx.x;
    if (e >= NE) return;
    const int r = ei[e];
    const int c = ei[NE + e];
    const int pos = offs[r] + bsum[r >> 9] + rank[e];   // no atomic
    quads[pos] = make_int4(e, r, c, 0);
}

// ---------------- MFMA edge kernel with in-kernel segmented reductions -------
// 512 thr = 8 waves, 128 CSR-ordered edges/block, 16 edges/wave.
// __launch_bounds__(512,6): LDS caps occupancy at 6 waves/EU anyway; this
// raises the VGPR budget 40 -> ~85 so B-frag loads can be batched/prefetched.

#define FSTR 168   // bf16 row stride (160 + 8 pad; 336B)

__global__ __launch_bounds__(512, 6) void edge_mfma_kernel(
    const unsigned short* __restrict__ hbf, const float* __restrict__ x,
    const float* __restrict__ ea,
    const unsigned short* __restrict__ W1p, const unsigned short* __restrict__ W2p,
    const unsigned short* __restrict__ Wc1p,
    const float* __restrict__ B1, const float* __restrict__ B2,
    const float* __restrict__ Bc1, const float* __restrict__ Wc2,
    const int4* __restrict__ quads,
    float* __restrict__ mf, float* __restrict__ xagg)
{
    __shared__ float sBias[256];        // B1 | B2 | Bc1 | Wc2
    __shared__ short sA[128 * FSTR];    // 43008 B
    __shared__ float sGeom[128 * 4];    // dx,dy,dz,dist
    __shared__ int   sRow[128];         // node id per slot
    __shared__ float sTrans[128][3];    // per-edge trans (block-local)

    const int tid = threadIdx.x;
    const int p0 = blockIdx.x * 128;

    if (tid < 64) {
        sBias[tid]       = B1[tid];
        sBias[64 + tid]  = B2[tid];
        sBias[128 + tid] = Bc1[tid];
        sBias[192 + tid] = Wc2[tid];
    }

    // stage features: 4 threads per edge slot
    {
        const int s = tid >> 2, q = tid & 3;
        const int4 pr = quads[p0 + s];
        const int eid = pr.x, row = pr.y, col = pr.z;

        const uint4* hr = (const uint4*)(hbf + (size_t)row * 64);
        *(uint4*)&sA[s * FSTR + q * 16]     = hr[q * 2];
        *(uint4*)&sA[s * FSTR + q * 16 + 8] = hr[q * 2 + 1];
        const uint4* hc = (const uint4*)(hbf + (size_t)col * 64);
        *(uint4*)&sA[s * FSTR + 64 + q * 16]     = hc[q * 2];
        *(uint4*)&sA[s * FSTR + 64 + q * 16 + 8] = hc[q * 2 + 1];

        const float4 e4 = ((const float4*)(ea + (size_t)eid * 16))[q];
        sA[s * FSTR + 129 + q * 4 + 0] = f2bf_hw(e4.x);
        sA[s * FSTR + 129 + q * 4 + 1] = f2bf_hw(e4.y);
        sA[s * FSTR + 129 + q * 4 + 2] = f2bf_hw(e4.z);
        sA[s * FSTR + 129 + q * 4 + 3] = f2bf_hw(e4.w);

        if (q == 0) {
            const float dx = x[row * 3 + 0] - x[col * 3 + 0];
            const float dy = x[row * 3 + 1] - x[col * 3 + 1];
            const float dz = x[row * 3 + 2] - x[col * 3 + 2];
            const float dist_sq = dx * dx + dy * dy + dz * dz;
            sGeom[s * 4 + 0] = dx;
            sGeom[s * 4 + 1] = dy;
            sGeom[s * 4 + 2] = dz;
            sGeom[s * 4 + 3] = sqrtf(dist_sq + EPS);
            sA[s * FSTR + 128] = f2bf_hw(log1pf(dist_sq));
        } else if (q == 1) {
            #pragma unroll
            for (int k = 145; k < 160; ++k) sA[s * FSTR + k] = 0;
        } else if (q == 2) {
            sRow[s] = row;
        }
    }
    __syncthreads();

    const int w = tid >> 6, l = tid & 63;
    const int lr = l & 15;
    const int ks = l >> 4;
    short* myA = &sA[(w * 16 + lr) * FSTR];

    // ---- msg layer 1: [16,160] @ [160,64], B via L1/L2 ----
    f32x4 acc[4];
    {
        const f32x4 b4 = *(const f32x4*)&sBias[lr * 4];
        #pragma unroll
        for (int nt = 0; nt < 4; ++nt)
            acc[nt] = (f32x4){b4[nt], b4[nt], b4[nt], b4[nt]};
    }
    #pragma unroll
    for (int c = 0; c < 5; ++c) {
        const bf16x8 af = *(const bf16x8*)&myA[c * 32 + ks * 8];
        #pragma unroll
        for (int nt = 0; nt < 4; ++nt) {
            const bf16x8 bf = *(const bf16x8*)&W1p[((c * 4 + nt) * 64 + l) * 8];
            acc[nt] = __builtin_amdgcn_mfma_f32_16x16x32_bf16(af, bf, acc[nt], 0, 0, 0);
        }
    }

    // prefetch W2 B-frags into registers (loads overlap layer-1 epilogue VALU)
    bf16x8 bw[8];
    #pragma unroll
    for (int c = 0; c < 2; ++c)
        #pragma unroll
        for (int nt = 0; nt < 4; ++nt)
            bw[c * 4 + nt] = *(const bf16x8*)&W2p[((c * 4 + nt) * 64 + l) * 8];

    {
        short* pw = &sA[(w * 16 + ks * 4) * FSTR + lr * 4];
        #pragma unroll
        for (int i = 0; i < 4; ++i) {
            uint2 u;
            u.x = pk2_hw(silu_f(acc[0][i]), silu_f(acc[1][i]));
            u.y = pk2_hw(silu_f(acc[2][i]), silu_f(acc[3][i]));
            *(uint2*)&pw[i * FSTR] = u;
        }
    }

    // ---- msg layer 2: [16,64] @ [64,64], B from prefetched regs ----
    f32x4 acc2[4];
    {
        const f32x4 b4 = *(const f32x4*)&sBias[64 + lr * 4];
        #pragma unroll
        for (int nt = 0; nt < 4; ++nt)
            acc2[nt] = (f32x4){b4[nt], b4[nt], b4[nt], b4[nt]};
    }
    #pragma unroll
    for (int c = 0; c < 2; ++c) {
        const bf16x8 af = *(const bf16x8*)&myA[c * 32 + ks * 8];
        #pragma unroll
        for (int nt = 0; nt < 4; ++nt)
            acc2[nt] = __builtin_amdgcn_mfma_f32_16x16x32_bf16(af, bw[c * 4 + nt], acc2[nt], 0, 0, 0);
    }

    // reload bw with Wc1 frags (loads overlap layer-2 epilogue VALU)
    #pragma unroll
    for (int c = 0; c < 2; ++c)
        #pragma unroll
        for (int nt = 0; nt < 4; ++nt)
            bw[c * 4 + nt] = *(const bf16x8*)&Wc1p[((c * 4 + nt) * 64 + l) * 8];

    {
        short* pw = &sA[(w * 16 + ks * 4) * FSTR + lr * 4];
        #pragma unroll
        for (int i = 0; i < 4; ++i) {
            uint2 u;
            u.x = pk2_hw(silu_f(acc2[0][i]), silu_f(acc2[1][i]));
            u.y = pk2_hw(silu_f(acc2[2][i]), silu_f(acc2[3][i]));
            *(uint2*)&pw[i * FSTR] = u;
        }
    }

    // ---- coord layer 1: [16,64] @ [64,64], input = m (cols 0..63) ----
    f32x4 acc3[4];
    {
        const f32x4 b4 = *(const f32x4*)&sBias[128 + lr * 4];
        #pragma unroll
        for (int nt = 0; nt < 4; ++nt)
            acc3[nt] = (f32x4){b4[nt], b4[nt], b4[nt], b4[nt]};
    }
    #pragma unroll
    for (int c = 0; c < 2; ++c) {
        const bf16x8 af = *(const bf16x8*)&myA[c * 32 + ks * 8];
        #pragma unroll
        for (int nt = 0; nt < 4; ++nt)
            acc3[nt] = __builtin_amdgcn_mfma_f32_16x16x32_bf16(af, bw[c * 4 + nt], acc3[nt], 0, 0, 0);
    }
    float part[4] = {0.0f, 0.0f, 0.0f, 0.0f};
    {
        const f32x4 w4 = *(const f32x4*)&sBias[192 + lr * 4];
        #pragma unroll
        for (int nt = 0; nt < 4; ++nt) {
            #pragma unroll
            for (int i = 0; i < 4; ++i) part[i] += silu_f(acc3[nt][i]) * w4[nt];
        }
    }
    #pragma unroll
    for (int m = 1; m <= 8; m <<= 1) {
        #pragma unroll
        for (int i = 0; i < 4; ++i) part[i] += __shfl_xor(part[i], m, 64);
    }
    if (lr == 0) {
        #pragma unroll
        for (int i = 0; i < 4; ++i) {
            const int slot = w * 16 + ks * 4 + i;
            const float dist = sGeom[slot * 4 + 3];
            const float g2 = fminf(fmaxf(2.0f * part[i], -30.0f), 30.0f);
            const float t = __expf(g2);
            const float th = (t - 1.0f) * rcp_fast(t + 1.0f);
            const float sc = th * 0.1f * rcp_fast(dist + EPS);
            sTrans[slot][0] = sGeom[slot * 4 + 0] * sc;
            sTrans[slot][1] = sGeom[slot * 4 + 1] * sc;
            sTrans[slot][2] = sGeom[slot * 4 + 2] * sc;
        }
    }

    // ---- m segmented reduce: wave reduces its OWN 16 rows (uniform branches),
    //      coalesced f32 atomics (64 consecutive floats per burst) ----
    {
        const int baserow = w * 16;
        int run_node = sRow[baserow];
        float runsum = 0.0f;
        #pragma unroll
        for (int r = 0; r < 16; ++r) {
            const int n = sRow[baserow + r];
            const float v = bf2f((unsigned short)sA[(baserow + r) * FSTR + l]);
            if (n != run_node) {
                atomicAdd(&mf[(size_t)run_node * 64 + l], runsum);
                run_node = n;
                runsum = v;
            } else {
                runsum += v;
            }
        }
        atomicAdd(&mf[(size_t)run_node * 64 + l], runsum);
    }

    // ---- trans segmented reduce: one walker thread per segment start ----
    __syncthreads();
    if (tid < 128) {
        const int s = tid;
        const int n = sRow[s];
        if (s == 0 || sRow[s - 1] != n) {
            float sx = 0.0f, sy = 0.0f, sz = 0.0f;
            int j = s;
            while (j < 128 && sRow[j] == n) {
                sx += sTrans[j][0];
                sy += sTrans[j][1];
                sz += sTrans[j][2];
                ++j;
            }
            atomicAdd(&xagg[n * 4 + 0], sx);
            atomicAdd(&xagg[n * 4 + 1], sy);
            atomicAdd(&xagg[n * 4 + 2], sz);
        }
    }
}

// ---------------- MFMA node kernel: MLP + residual + LayerNorm + x finalize --

#define NSTR 136   // 128 + 8 pad

__global__ __launch_bounds__(256) void node_mfma_kernel(
    const unsigned short* __restrict__ hbf, const float* __restrict__ mf,
    const int* __restrict__ counts,
    const unsigned short* __restrict__ Wn1p, const unsigned short* __restrict__ Wn2p,
    const float* __restrict__ Bn1, const float* __restrict__ Bn2,
    const float* __restrict__ ln_g, const float* __restrict__ ln_b,
    const float* __restrict__ x, const float* __restrict__ xagg,
    float* __restrict__ h_out, float* __restrict__ x_out)
{
    __shared__ short sA[64 * NSTR];   // 17408 B
    __shared__ float sBias[256];      // Bn1 | Bn2 | g | b

    const int tid = threadIdx.x;
    const int n0 = blockIdx.x * 64;

    if (tid < 64) {
        sBias[tid]       = Bn1[tid];
        sBias[64 + tid]  = Bn2[tid];
        sBias[128 + tid] = ln_g[tid];
        sBias[192 + tid] = ln_b[tid];
    }
    {
        const int s = tid >> 2, q = tid & 3;
        const int node = n0 + s;
        const int n = (node < NN) ? node : (NN - 1);
        const uint4* hr = (const uint4*)(hbf + (size_t)n * 64);
        *(uint4*)&sA[s * NSTR + q * 16]     = hr[q * 2];
        *(uint4*)&sA[s * NSTR + q * 16 + 8] = hr[q * 2 + 1];
        // m_i = mf / (count + EPS), f32 -> bf16
        const float inv = rcp_fast((float)counts[n] + EPS);
        const float4* mr = (const float4*)(mf + (size_t)n * 64) + q * 4;
        #pragma unroll
        for (int c2 = 0; c2 < 2; ++c2) {
            const float4 a = mr[c2 * 2], b = mr[c2 * 2 + 1];
            uint4 u;
            u.x = pk2_hw(a.x * inv, a.y * inv); u.y = pk2_hw(a.z * inv, a.w * inv);
            u.z = pk2_hw(b.x * inv, b.y * inv); u.w = pk2_hw(b.z * inv, b.w * inv);
            *(uint4*)&sA[s * NSTR + 64 + q * 16 + c2 * 8] = u;
        }
    }
    __syncthreads();

    const int w = tid >> 6, l = tid & 63;
    const int lr = l & 15;
    const int ks = l >> 4;
    const short* myA = &sA[(w * 16 + lr) * NSTR];

    // ---- node layer 1: [16,128] @ [128,64] ----
    f32x4 acc[4];
    {
        const f32x4 b4 = *(const f32x4*)&sBias[lr * 4];
        #pragma unroll
        for (int nt = 0; nt < 4; ++nt)
            acc[nt] = (f32x4){b4[nt], b4[nt], b4[nt], b4[nt]};
    }
    #pragma unroll
    for (int c = 0; c < 4; ++c) {
        const bf16x8 af = *(const bf16x8*)&myA[c * 32 + ks * 8];
        #pragma unroll
        for (int nt = 0; nt < 4; ++nt) {
            const bf16x8 bf = *(const bf16x8*)&Wn1p[((c * 4 + nt) * 64 + l) * 8];
            acc[nt] = __builtin_amdgcn_mfma_f32_16x16x32_bf16(af, bf, acc[nt], 0, 0, 0);
        }
    }
    // silu -> cols 64..127 (channel-perm packed writes)
    {
        short* pw = &sA[(w * 16 + ks * 4) * NSTR + 64 + lr * 4];
        #pragma unroll
        for (int i = 0; i < 4; ++i) {
            uint2 u;
            u.x = pk2_hw(silu_f(acc[0][i]), silu_f(acc[1][i]));
            u.y = pk2_hw(silu_f(acc[2][i]), silu_f(acc[3][i]));
            *(uint2*)&pw[i * NSTR] = u;
        }
    }

    // ---- node layer 2: [16,64] @ [64,64] ----
    f32x4 acc2[4];
    {
        const f32x4 b4 = *(const f32x4*)&sBias[64 + lr * 4];
        #pragma unroll
        for (int nt = 0; nt < 4; ++nt)
            acc2[nt] = (f32x4){b4[nt], b4[nt], b4[nt], b4[nt]};
    }
    #pragma unroll
    for (int c = 0; c < 2; ++c) {
        const bf16x8 af = *(const bf16x8*)&myA[64 + c * 32 + ks * 8];
        #pragma unroll
        for (int nt = 0; nt < 4; ++nt) {
            const bf16x8 bf = *(const bf16x8*)&Wn2p[((c * 4 + nt) * 64 + l) * 8];
            acc2[nt] = __builtin_amdgcn_mfma_f32_16x16x32_bf16(af, bf, acc2[nt], 0, 0, 0);
        }
    }

    // residual: thread's 4 nt channels are contiguous (lr*4..+3) -> b64 read
    float a2[4][4];
    #pragma unroll
    for (int i = 0; i < 4; ++i) {
        const uint2 hres = *(const uint2*)&sA[(w * 16 + ks * 4 + i) * NSTR + lr * 4];
        a2[0][i] = acc2[0][i] + bf2f((unsigned short)(hres.x & 0xffffu));
        a2[1][i] = acc2[1][i] + bf2f((unsigned short)(hres.x >> 16));
        a2[2][i] = acc2[2][i] + bf2f((unsigned short)(hres.y & 0xffffu));
        a2[3][i] = acc2[3][i] + bf2f((unsigned short)(hres.y >> 16));
    }

    float su[4];
    #pragma unroll
    for (int i = 0; i < 4; ++i)
        su[i] = a2[0][i] + a2[1][i] + a2[2][i] + a2[3][i];
    #pragma unroll
    for (int m = 1; m <= 8; m <<= 1)
        #pragma unroll
        for (int i = 0; i < 4; ++i) su[i] += __shfl_xor(su[i], m, 64);
    float mu[4];
    #pragma unroll
    for (int i = 0; i < 4; ++i) mu[i] = su[i] * (1.0f / 64.0f);

    float sv[4];
    #pragma unroll
    for (int i = 0; i < 4; ++i) {
        float s = 0.0f;
        #pragma unroll
        for (int nt = 0; nt < 4; ++nt) {
            const float d = a2[nt][i] - mu[i];
            s += d * d;
        }
        sv[i] = s;
    }
    #pragma unroll
    for (int m = 1; m <= 8; m <<= 1)
        #pragma unroll
        for (int i = 0; i < 4; ++i) sv[i] += __shfl_xor(sv[i], m, 64);

    {
        const f32x4 g4 = *(const f32x4*)&sBias[128 + lr * 4];
        const f32x4 b4 = *(const f32x4*)&sBias[192 + lr * 4];
        #pragma unroll
        for (int i = 0; i < 4; ++i) {
            const float rstd = rsqrtf(sv[i] * (1.0f / 64.0f) + LN_EPS);
            const int node = n0 + w * 16 + ks * 4 + i;
            if (node < NN) {
                float4 o;
                o.x = (a2[0][i] - mu[i]) * rstd * g4[0] + b4[0];
                o.y = (a2[1][i] - mu[i]) * rstd * g4[1] + b4[1];
                o.z = (a2[2][i] - mu[i]) * rstd * g4[2] + b4[2];
                o.w = (a2[3][i] - mu[i]) * rstd * g4[3] + b4[3];
                *(float4*)&h_out[(size_t)node * 64 + lr * 4] = o;
            }
        }
    }

    // ---- fused x finalize: one thread per node ----
    if (tid < 64) {
        const int n = n0 + tid;
        if (n < NN) {
            const float inv = rcp_fast((float)counts[n] + EPS);
            x_out[(size_t)n * 3 + 0] = x[(size_t)n * 3 + 0] + xagg[n * 4 + 0] * inv;
            x_out[(size_t)n * 3 + 1] = x[(size_t)n * 3 + 1] + xagg[n * 4 + 1] * inv;
            x_out[(size_t)n * 3 + 2] = x[(size_t)n * 3 + 2] + xagg[n * 4 + 2] * inv;
        }
    }
}

// ---------------- fallback (atomic path, minimal ws) ----------------

__global__ __launch_bounds__(64) void edge_atomic_kernel(
    const float* __restrict__ h, const float* __restrict__ x,
    const int* __restrict__ ei, const float* __restrict__ ea,
    const float* __restrict__ W1, const float* __restrict__ B1,
    const float* __restrict__ W2, const float* __restrict__ B2,
    const float* __restrict__ Wc1, const float* __restrict__ Bc1,
    const float* __restrict__ Wc2,
    float* __restrict__ m_acc, float* __restrict__ xagg)
{
    __shared__ float lds[64 * 64];
    const int lane = threadIdx.x;
    const int e = blockIdx.x * 64 + lane;

    const int row = ei[e];
    const int col = ei[NE + e];

    const float dx = x[row * 3 + 0] - x[col * 3 + 0];
    const float dy = x[row * 3 + 1] - x[col * 3 + 1];
    const float dz = x[row * 3 + 2] - x[col * 3 + 2];
    const float dist_sq = dx * dx + dy * dy + dz * dz;
    const float dist = sqrtf(dist_sq + EPS);
    const float logd = log1pf(dist_sq);

    float a1[64];
    #pragma unroll
    for (int j = 0; j < 64; ++j) a1[j] = B1[j];
    const float4* hr4 = (const float4*)(h + (size_t)row * 64);
    for (int k4 = 0; k4 < 16; ++k4) {
        const float4 v4 = hr4[k4];
        #pragma unroll
        for (int c = 0; c < 4; ++c) {
            const float v = (c == 0) ? v4.x : (c == 1) ? v4.y : (c == 2) ? v4.z : v4.w;
            const float* w = W1 + (k4 * 4 + c) * 64;
            #pragma unroll
            for (int j = 0; j < 64; ++j) a1[j] = fmaf(v, w[j], a1[j]);
        }
    }
    const float4* hc4 = (const float4*)(h + (size_t)col * 64);
    for (int k4 = 0; k4 < 16; ++k4) {
        const float4 v4 = hc4[k4];
        #pragma unroll
        for (int c = 0; c < 4; ++c) {
            const float v = (c == 0) ? v4.x : (c == 1) ? v4.y : (c == 2) ? v4.z : v4.w;
            const float* w = W1 + (64 + k4 * 4 + c) * 64;
            #pragma unroll
            for (int j = 0; j < 64; ++j) a1[j] = fmaf(v, w[j], a1[j]);
        }
    }
    {
        const float* w = W1 + 128 * 64;
        #pragma unroll
        for (int j = 0; j < 64; ++j) a1[j] = fmaf(logd, w[j], a1[j]);
    }
    const float4* ea4 = (const float4*)(ea + (size_t)e * 16);
    for (int k4 = 0; k4 < 4; ++k4) {
        const float4 v4 = ea4[k4];
        #pragma unroll
        for (int c = 0; c < 4; ++c) {
            const float v = (c == 0) ? v4.x : (c == 1) ? v4.y : (c == 2) ? v4.z : v4.w;
            const float* w = W1 + (129 + k4 * 4 + c) * 64;
            #pragma unroll
            for (int j = 0; j < 64; ++j) a1[j] = fmaf(v, w[j], a1[j]);
        }
    }

    #pragma unroll
    for (int j = 0; j < 64; ++j) lds[j * 64 + lane] = silu_f(a1[j]);

    float a2[64];
    #pragma unroll
    for (int j = 0; j < 64; ++j) a2[j] = B2[j];
    for (int k = 0; k < 64; ++k) {
        const float v = lds[k * 64 + lane];
        const float* w = W2 + k * 64;
        #pragma unroll
        for (int j = 0; j < 64; ++j) a2[j] = fmaf(v, w[j], a2[j]);
    }

    float* mrow = m_acc + (size_t)row * 64;
    #pragma unroll
    for (int j = 0; j < 64; ++j) {
        const float mj = silu_f(a2[j]);
        lds[j * 64 + lane] = mj;
        atomicAdd(mrow + j, mj);
    }

    float t[64];
    #pragma unroll
    for (int j = 0; j < 64; ++j) t[j] = Bc1[j];
    for (int k = 0; k < 64; ++k) {
        const float v = lds[k * 64 + lane];
        const float* w = Wc1 + k * 64;
        #pragma unroll
        for (int j = 0; j < 64; ++j) t[j] = fmaf(v, w[j], t[j]);
    }
    float g = 0.0f;
    #pragma unroll
    for (int j = 0; j < 64; ++j) g += silu_f(t[j]) * Wc2[j];

    const float s = tanhf(g) * 0.1f / (dist + EPS);
    atomicAdd(&xagg[row * 4 + 0], dx * s);
    atomicAdd(&xagg[row * 4 + 1], dy * s);
    atomicAdd(&xagg[row * 4 + 2], dz * s);
    atomicAdd(&xagg[row * 4 + 3], 1.0f);
}

__global__ __launch_bounds__(64) void node_csr_kernel(
    const float* __restrict__ h,
    const float* __restrict__ m_i,
    const float* __restrict__ Wn1, const float* __restrict__ Bn1,
    const float* __restrict__ Wn2, const float* __restrict__ Bn2,
    const float* __restrict__ ln_g, const float* __restrict__ ln_b,
    float* __restrict__ h_out)
{
    __shared__ float lds[64 * 64];
    const int lane = threadIdx.x;
    const int node = blockIdx.x * 64 + lane;
    const bool act = node < NN;
    const int n = act ? node : 0;

    float a1[64];
    #pragma unroll
    for (int j = 0; j < 64; ++j) a1[j] = Bn1[j];

    const float* hr = h + (size_t)n * 64;
    const float4* hr4 = (const float4*)hr;
    for (int k4 = 0; k4 < 16; ++k4) {
        const float4 v4 = hr4[k4];
        #pragma unroll
        for (int c = 0; c < 4; ++c) {
            const float v = (c == 0) ? v4.x : (c == 1) ? v4.y : (c == 2) ? v4.z : v4.w;
            const float* w = Wn1 + (k4 * 4 + c) * 64;
            #pragma unroll
            for (int j = 0; j < 64; ++j) a1[j] = fmaf(v, w[j], a1[j]);
        }
    }
    const float4* mr4 = (const float4*)(m_i + (size_t)n * 64);
    for (int k4 = 0; k4 < 16; ++k4) {
        const float4 v4 = mr4[k4];
        #pragma unroll
        for (int c = 0; c < 4; ++c) {
            const float v = (c == 0) ? v4.x : (c == 1) ? v4.y : (c == 2) ? v4.z : v4.w;
            const float* w = Wn1 + (64 + k4 * 4 + c) * 64;
            #pragma unroll
            for (int j = 0; j < 64; ++j) a1[j] = fmaf(v, w[j], a1[j]);
        }
    }

    #pragma unroll
    for (int j = 0; j < 64; ++j) lds[j * 64 + lane] = silu_f(a1[j]);

    float a2[64];
    #pragma unroll
    for (int j = 0; j < 64; ++j) a2[j] = Bn2[j];
    for (int k = 0; k < 64; ++k) {
        const float v = lds[k * 64 + lane];
        const float* w = Wn2 + k * 64;
        #pragma unroll
        for (int j = 0; j < 64; ++j) a2[j] = fmaf(v, w[j], a2[j]);
    }

    float mu = 0.0f;
    #pragma unroll
    for (int j = 0; j < 64; ++j) { a2[j] += hr[j]; mu += a2[j]; }
    mu *= (1.0f / 64.0f);
    float var = 0.0f;
    #pragma unroll
    for (int j = 0; j < 64; ++j) { const float d = a2[j] - mu; var += d * d; }
    var *= (1.0f / 64.0f);
    const float rstd = rsqrtf(var + LN_EPS);

    if (act) {
        #pragma unroll
        for (int j = 0; j < 64; ++j)
            h_out[(size_t)n * 64 + j] = (a2[j] - mu) * rstd * ln_g[j] + ln_b[j];
    }
}

__global__ void x_atomic_kernel(const float* __restrict__ x, const float* __restrict__ xagg,
                                float* __restrict__ x_out)
{
    const int i = blockIdx.x * 256 + threadIdx.x;
    if (i >= NN) return;
    const float inv_cnt = 1.0f / (xagg[i * 4 + 3] + EPS);
    #pragma unroll
    for (int c = 0; c < 3; ++c)
        x_out[(size_t)i * 3 + c] = x[(size_t)i * 3 + c] + xagg[i * 4 + c] * inv_cnt;
}

__global__ void div_m_kernel(float* __restrict__ m_acc, const float* __restrict__ xagg) {
    const int i = blockIdx.x * 256 + threadIdx.x;
    if (i >= NN * 64) return;
    m_acc[i] /= (xagg[(i >> 6) * 4 + 3] + EPS);
}

// ---------------- launch ----------------

extern "C" void kernel_launch(void* const* d_in, const int* in_sizes, int n_in,
                              void* d_out, int out_size, void* d_ws, size_t ws_size,
                              hipStream_t stream)
{
    const float* h   = (const float*)d_in[0];
    const float* x   = (const float*)d_in[1];
    const int*   ei  = (const int*)d_in[2];
    const float* ea  = (const float*)d_in[3];
    const float* W1  = (const float*)d_in[4];
    const float* B1  = (const float*)d_in[5];
    const float* W2  = (const float*)d_in[6];
    const float* B2  = (const float*)d_in[7];
    const float* Wn1 = (const float*)d_in[8];
    const float* Bn1 = (const float*)d_in[9];
    const float* Wn2 = (const float*)d_in[10];
    const float* Bn2 = (const float*)d_in[11];
    const float* Wc1 = (const float*)d_in[12];
    const float* Bc1 = (const float*)d_in[13];
    const float* Wc2 = (const float*)d_in[14];
    const float* lng = (const float*)d_in[15];
    const float* lnb = (const float*)d_in[16];

    float* out   = (float*)d_out;
    float* x_out = out + (size_t)NN * 64;

    size_t off = 0;
    auto take = [&](size_t bytes) { size_t p = off; off = (off + bytes + 255) & ~(size_t)255; return p; };
    char* ws = (char*)d_ws;
    const size_t o_quads  = take((size_t)NE * 16);         // int4 {eid,row,col,-}
    const size_t o_counts = take((size_t)NN * 4);
    const size_t o_rank   = take((size_t)NE * 4);          // within-node rank per edge
    const size_t o_offs   = take((size_t)(NN + 1) * 4);
    const size_t o_bsum   = take((size_t)1024 * 4);
    const size_t o_hbf    = take((size_t)NN * 64 * 2);     // bf16 h
    const size_t o_mf     = take((size_t)NN * 64 * 4);     // f32 m sum accumulator
    const size_t o_xagg   = take((size_t)NN * 4 * 4);      // f32 x aggregate
    const size_t o_w1p    = take((size_t)10240 * 2);
    const size_t o_w2p    = take((size_t)4096 * 2);
    const size_t o_wc1p   = take((size_t)4096 * 2);
    const size_t o_wn1p   = take((size_t)8192 * 2);
    const size_t o_wn2p   = take((size_t)4096 * 2);
    const size_t need = off;

    if (ws_size >= need) {
        int4*  quads  = (int4*)(ws + o_quads);
        int*   counts = (int*)(ws + o_counts);
        int*   rank   = (int*)(ws + o_rank);
        int*   offs   = (int*)(ws + o_offs);
        int*   bsum   = (int*)(ws + o_bsum);
        unsigned short* hbf   = (unsigned short*)(ws + o_hbf);
        float* mf     = (float*)(ws + o_mf);
        float* xagg   = (float*)(ws + o_xagg);
        unsigned short* W1p   = (unsigned short*)(ws + o_w1p);
        unsigned short* W2p   = (unsigned short*)(ws + o_w2p);
        unsigned short* Wc1p  = (unsigned short*)(ws + o_wc1p);
        unsigned short* Wn1p  = (unsigned short*)(ws + o_wn1p);
        unsigned short* Wn2p  = (unsigned short*)(ws + o_wn2p);

        hipMemsetAsync(counts, 0, (size_t)NN * 4, stream);
        hipMemsetAsync(mf, 0, (size_t)NN * 64 * 4, stream);
        hipMemsetAsync(xagg, 0, (size_t)NN * 4 * 4, stream);

        prep_count_kernel<<<HB_BLOCKS + PW_BLOCKS + CNT_BLOCKS, 256, 0, stream>>>(
            h, W1, W2, Wc1, Wn1, Wn2, ei,
            hbf, W1p, W2p, Wc1p, Wn1p, Wn2p, counts, rank);

        const int nblk = (NN + SCAN_B - 1) / SCAN_B;
        scan1_kernel<<<nblk, SCAN_B, 0, stream>>>(counts, offs, bsum);
        scan2_kernel<<<1, SCAN_B, 0, stream>>>(bsum, nblk);
        scatter_kernel<<<(NE + 255) / 256, 256, 0, stream>>>(ei, offs, bsum, rank, quads);

        edge_mfma_kernel<<<NE / 128, 512, 0, stream>>>(hbf, x, ea, W1p, W2p, Wc1p,
                                                       B1, B2, Bc1, Wc2, quads,
                                                       mf, xagg);
        node_mfma_kernel<<<(NN + 63) / 64, 256, 0, stream>>>(hbf, mf, counts, Wn1p, Wn2p,
                                                             Bn1, Bn2, lng, lnb,
                                                             x, xagg, out, x_out);
    } else {
        float* m_acc = out;
        float* xagg  = (float*)d_ws;
        hipMemsetAsync(m_acc, 0, (size_t)NN * 64 * 4, stream);
        hipMemsetAsync(xagg, 0, (size_t)NN * 4 * 4, stream);
        edge_atomic_kernel<<<NE / 64, 64, 0, stream>>>(h, x, ei, ea, W1, B1, W2, B2,
                                                       Wc1, Bc1, Wc2, m_acc, xagg);
        div_m_kernel<<<(NN * 64 + 255) / 256, 256, 0, stream>>>(m_acc, xagg);
        node_csr_kernel<<<(NN + 63) / 64, 64, 0, stream>>>(h, m_acc, Wn1, Bn1, Wn2, Bn2,
                                                           lng, lnb, m_acc);
        x_atomic_kernel<<<(NN + 255) / 256, 256, 0, stream>>>(x, xagg, m_acc + (size_t)NN * 64);
    }
}

// Round 10
// 361.696 us; speedup vs baseline: 1.0274x; 1.0274x over previous
//
#include <hip/hip_runtime.h>
#include <hip/hip_bf16.h>
#include <math.h>

#define NN 100000
#define NE 1600000

constexpr float EPS = 1e-8f;
constexpr float LN_EPS = 1e-5f;

typedef short bf16x8 __attribute__((ext_vector_type(8)));
typedef float f32x4 __attribute__((ext_vector_type(4)));

__device__ __forceinline__ float rcp_fast(float v) {
    return __builtin_amdgcn_rcpf(v);
}
__device__ __forceinline__ float silu_f(float v) {
    return v * rcp_fast(1.0f + __expf(-v));
}
__device__ __forceinline__ short f2bf_hw(float v) {
    union { __hip_bfloat16 b; short s; } u;
    u.b = __float2bfloat16(v);
    return u.s;
}
__device__ __forceinline__ unsigned int pk2_hw(float lo, float hi) {
    union { __hip_bfloat162 b2; unsigned int u; } u;
    u.b2 = __float22bfloat162_rn(make_float2(lo, hi));
    return u.u;
}
__device__ __forceinline__ float bf2f(unsigned short s) {
    return __uint_as_float(((unsigned int)s) << 16);
}

// ---------------- fused prep: bf16 h + frag-packed weights + count+rank ------
// frag order: elem ((c*4+nt)*64 + l)*8 + j  ==  W[k = c*32+(l>>4)*8+j][n]
// OUTPUT-CHANNEL PERM: n = (l&15)*4 + nt

#define HB_BLOCKS 6250      // NN*64/4/256
#define PW_BLOCKS 120
#define CNT_BLOCKS 6250     // NE/256

__global__ void prep_count_kernel(const float* __restrict__ h,
                            const float* __restrict__ W1, const float* __restrict__ W2,
                            const float* __restrict__ Wc1,
                            const float* __restrict__ Wn1, const float* __restrict__ Wn2,
                            const int* __restrict__ ei,
                            unsigned short* __restrict__ hbf,
                            unsigned short* __restrict__ W1p, unsigned short* __restrict__ W2p,
                            unsigned short* __restrict__ Wc1p,
                            unsigned short* __restrict__ Wn1p, unsigned short* __restrict__ Wn2p,
                            int* __restrict__ counts, int* __restrict__ rank)
{
    const int b = blockIdx.x;
    if (b < HB_BLOCKS) {
        const int i = b * 256 + threadIdx.x;     // 4 elems each
        const float4 v = ((const float4*)h)[i];
        uint2 u; u.x = pk2_hw(v.x, v.y); u.y = pk2_hw(v.z, v.w);
        ((uint2*)hbf)[i] = u;
        return;
    }
    if (b < HB_BLOCKS + PW_BLOCKS) {
        const int idx = (b - HB_BLOCKS) * 256 + threadIdx.x;
        if (idx < 10240) {                           // W1: K=160 (145 real)
            const int j = idx & 7, l = (idx >> 3) & 63, nt = (idx >> 9) & 3, c = idx >> 11;
            const int k = c * 32 + (l >> 4) * 8 + j, n = (l & 15) * 4 + nt;
            W1p[idx] = (k < 145) ? (unsigned short)f2bf_hw(W1[k * 64 + n]) : (unsigned short)0;
        } else if (idx < 14336) {                    // W2: K=64
            const int t = idx - 10240;
            const int j = t & 7, l = (t >> 3) & 63, nt = (t >> 9) & 3, c = t >> 11;
            W2p[t] = (unsigned short)f2bf_hw(W2[(c * 32 + (l >> 4) * 8 + j) * 64 + (l & 15) * 4 + nt]);
        } else if (idx < 18432) {                    // Wc1: K=64
            const int t = idx - 14336;
            const int j = t & 7, l = (t >> 3) & 63, nt = (t >> 9) & 3, c = t >> 11;
            Wc1p[t] = (unsigned short)f2bf_hw(Wc1[(c * 32 + (l >> 4) * 8 + j) * 64 + (l & 15) * 4 + nt]);
        } else if (idx < 26624) {                    // Wn1: K=128
            const int t = idx - 18432;
            const int j = t & 7, l = (t >> 3) & 63, nt = (t >> 9) & 3, c = t >> 11;
            Wn1p[t] = (unsigned short)f2bf_hw(Wn1[(c * 32 + (l >> 4) * 8 + j) * 64 + (l & 15) * 4 + nt]);
        } else if (idx < 30720) {                    // Wn2: K=64
            const int t = idx - 26624;
            const int j = t & 7, l = (t >> 3) & 63, nt = (t >> 9) & 3, c = t >> 11;
            Wn2p[t] = (unsigned short)f2bf_hw(Wn2[(c * 32 + (l >> 4) * 8 + j) * 64 + (l & 15) * 4 + nt]);
        }
        return;
    }
    // count + rank in one atomic pass: the returned old value IS the rank
    const int e = (b - HB_BLOCKS - PW_BLOCKS) * 256 + threadIdx.x;
    if (e < NE) rank[e] = atomicAdd(&counts[ei[e]], 1);
}

// ---------------- CSR build (scan + fused atomic-free scatter) ----------------

#define SCAN_B 512
__global__ __launch_bounds__(SCAN_B) void scan1_kernel(const int* __restrict__ counts,
                                                       int* __restrict__ offs,
                                                       int* __restrict__ bsum) {
    __shared__ int s[SCAN_B];
    const int tid = threadIdx.x;
    const int idx = blockIdx.x * SCAN_B + tid;
    const int v = (idx < NN) ? counts[idx] : 0;
    s[tid] = v;
    __syncthreads();
    for (int off = 1; off < SCAN_B; off <<= 1) {
        const int t = (tid >= off) ? s[tid - off] : 0;
        __syncthreads();
        s[tid] += t;
        __syncthreads();
    }
    if (idx < NN) offs[idx] = s[tid] - v;         // block-local exclusive
    if (tid == SCAN_B - 1) bsum[blockIdx.x] = s[tid];
}

__global__ __launch_bounds__(SCAN_B) void scan2_kernel(int* __restrict__ bsum, int nblk) {
    __shared__ int s[SCAN_B];
    const int tid = threadIdx.x;
    const int v = (tid < nblk) ? bsum[tid] : 0;
    s[tid] = v;
    __syncthreads();
    for (int off = 1; off < SCAN_B; off <<= 1) {
        const int t = (tid >= off) ? s[tid - off] : 0;
        __syncthreads();
        s[tid] += t;
        __syncthreads();
    }
    if (tid < nblk) bsum[tid] = s[tid] - v;       // exclusive
}

// scatter with fused block-sum add (no scan3 pass)
__global__ void scatter_kernel(const int* __restrict__ ei, const int* __restrict__ offs,
                               const int* __restrict__ bsum, const int* __restrict__ rank,
                               int4* __restrict__ quads) {
    const int e = blockIdx.x * 256 + threadIdx.x;
    if (e >= NE) return;
    const int r = ei[e];
    const int c = ei[NE + e];
    const int pos = offs[r] + bsum[r >> 9] + rank[e];   // no atomic
    quads[pos] = make_int4(e, r, c, 0);
}

// ---------------- MFMA edge kernel with in-kernel segmented reductions -------
// 512 thr = 8 waves, 128 CSR-ordered edges/block, 16 edges/wave.
// BOTH reductions are wave-local (uniform branches, partial sums + atomics);
// only ONE barrier in the whole kernel (after staging).

#define FSTR 168   // bf16 row stride (160 + 8 pad; 336B)

__global__ __launch_bounds__(512, 6) void edge_mfma_kernel(
    const unsigned short* __restrict__ hbf, const float* __restrict__ x,
    const float* __restrict__ ea,
    const unsigned short* __restrict__ W1p, const unsigned short* __restrict__ W2p,
    const unsigned short* __restrict__ Wc1p,
    const float* __restrict__ B1, const float* __restrict__ B2,
    const float* __restrict__ Bc1, const float* __restrict__ Wc2,
    const int4* __restrict__ quads,
    float* __restrict__ mf, float* __restrict__ xagg)
{
    __shared__ float sBias[256];        // B1 | B2 | Bc1 | Wc2
    __shared__ short sA[128 * FSTR];    // 43008 B
    __shared__ float sGeom[128 * 4];    // dx,dy,dz,dist
    __shared__ int   sRow[128];         // node id per slot
    __shared__ float sTrans[128][3];    // per-edge trans (wave-local use)

    const int tid = threadIdx.x;
    const int p0 = blockIdx.x * 128;

    if (tid < 64) {
        sBias[tid]       = B1[tid];
        sBias[64 + tid]  = B2[tid];
        sBias[128 + tid] = Bc1[tid];
        sBias[192 + tid] = Wc2[tid];
    }

    // stage features: 4 threads per edge slot
    {
        const int s = tid >> 2, q = tid & 3;
        const int4 pr = quads[p0 + s];
        const int eid = pr.x, row = pr.y, col = pr.z;

        const uint4* hr = (const uint4*)(hbf + (size_t)row * 64);
        *(uint4*)&sA[s * FSTR + q * 16]     = hr[q * 2];
        *(uint4*)&sA[s * FSTR + q * 16 + 8] = hr[q * 2 + 1];
        const uint4* hc = (const uint4*)(hbf + (size_t)col * 64);
        *(uint4*)&sA[s * FSTR + 64 + q * 16]     = hc[q * 2];
        *(uint4*)&sA[s * FSTR + 64 + q * 16 + 8] = hc[q * 2 + 1];

        const float4 e4 = ((const float4*)(ea + (size_t)eid * 16))[q];
        sA[s * FSTR + 129 + q * 4 + 0] = f2bf_hw(e4.x);
        sA[s * FSTR + 129 + q * 4 + 1] = f2bf_hw(e4.y);
        sA[s * FSTR + 129 + q * 4 + 2] = f2bf_hw(e4.z);
        sA[s * FSTR + 129 + q * 4 + 3] = f2bf_hw(e4.w);

        if (q == 0) {
            const float dx = x[row * 3 + 0] - x[col * 3 + 0];
            const float dy = x[row * 3 + 1] - x[col * 3 + 1];
            const float dz = x[row * 3 + 2] - x[col * 3 + 2];
            const float dist_sq = dx * dx + dy * dy + dz * dz;
            sGeom[s * 4 + 0] = dx;
            sGeom[s * 4 + 1] = dy;
            sGeom[s * 4 + 2] = dz;
            sGeom[s * 4 + 3] = sqrtf(dist_sq + EPS);
            sA[s * FSTR + 128] = f2bf_hw(log1pf(dist_sq));
        } else if (q == 1) {
            #pragma unroll
            for (int k = 145; k < 160; ++k) sA[s * FSTR + k] = 0;
        } else if (q == 2) {
            sRow[s] = row;
        }
    }
    __syncthreads();

    const int w = tid >> 6, l = tid & 63;
    const int lr = l & 15;
    const int ks = l >> 4;
    short* myA = &sA[(w * 16 + lr) * FSTR];

    // ---- msg layer 1: [16,160] @ [160,64], B via L1/L2 ----
    f32x4 acc[4];
    {
        const f32x4 b4 = *(const f32x4*)&sBias[lr * 4];
        #pragma unroll
        for (int nt = 0; nt < 4; ++nt)
            acc[nt] = (f32x4){b4[nt], b4[nt], b4[nt], b4[nt]};
    }
    #pragma unroll
    for (int c = 0; c < 5; ++c) {
        const bf16x8 af = *(const bf16x8*)&myA[c * 32 + ks * 8];
        #pragma unroll
        for (int nt = 0; nt < 4; ++nt) {
            const bf16x8 bf = *(const bf16x8*)&W1p[((c * 4 + nt) * 64 + l) * 8];
            acc[nt] = __builtin_amdgcn_mfma_f32_16x16x32_bf16(af, bf, acc[nt], 0, 0, 0);
        }
    }

    // prefetch W2 B-frags (kept; codegen-neutral but documents intent)
    bf16x8 bw[8];
    #pragma unroll
    for (int c = 0; c < 2; ++c)
        #pragma unroll
        for (int nt = 0; nt < 4; ++nt)
            bw[c * 4 + nt] = *(const bf16x8*)&W2p[((c * 4 + nt) * 64 + l) * 8];

    {
        short* pw = &sA[(w * 16 + ks * 4) * FSTR + lr * 4];
        #pragma unroll
        for (int i = 0; i < 4; ++i) {
            uint2 u;
            u.x = pk2_hw(silu_f(acc[0][i]), silu_f(acc[1][i]));
            u.y = pk2_hw(silu_f(acc[2][i]), silu_f(acc[3][i]));
            *(uint2*)&pw[i * FSTR] = u;
        }
    }

    // ---- msg layer 2: [16,64] @ [64,64] ----
    f32x4 acc2[4];
    {
        const f32x4 b4 = *(const f32x4*)&sBias[64 + lr * 4];
        #pragma unroll
        for (int nt = 0; nt < 4; ++nt)
            acc2[nt] = (f32x4){b4[nt], b4[nt], b4[nt], b4[nt]};
    }
    #pragma unroll
    for (int c = 0; c < 2; ++c) {
        const bf16x8 af = *(const bf16x8*)&myA[c * 32 + ks * 8];
        #pragma unroll
        for (int nt = 0; nt < 4; ++nt)
            acc2[nt] = __builtin_amdgcn_mfma_f32_16x16x32_bf16(af, bw[c * 4 + nt], acc2[nt], 0, 0, 0);
    }

    // reload bw with Wc1 frags
    #pragma unroll
    for (int c = 0; c < 2; ++c)
        #pragma unroll
        for (int nt = 0; nt < 4; ++nt)
            bw[c * 4 + nt] = *(const bf16x8*)&Wc1p[((c * 4 + nt) * 64 + l) * 8];

    {
        short* pw = &sA[(w * 16 + ks * 4) * FSTR + lr * 4];
        #pragma unroll
        for (int i = 0; i < 4; ++i) {
            uint2 u;
            u.x = pk2_hw(silu_f(acc2[0][i]), silu_f(acc2[1][i]));
            u.y = pk2_hw(silu_f(acc2[2][i]), silu_f(acc2[3][i]));
            *(uint2*)&pw[i * FSTR] = u;
        }
    }

    // ---- coord layer 1: [16,64] @ [64,64], input = m (cols 0..63) ----
    f32x4 acc3[4];
    {
        const f32x4 b4 = *(const f32x4*)&sBias[128 + lr * 4];
        #pragma unroll
        for (int nt = 0; nt < 4; ++nt)
            acc3[nt] = (f32x4){b4[nt], b4[nt], b4[nt], b4[nt]};
    }
    #pragma unroll
    for (int c = 0; c < 2; ++c) {
        const bf16x8 af = *(const bf16x8*)&myA[c * 32 + ks * 8];
        #pragma unroll
        for (int nt = 0; nt < 4; ++nt)
            acc3[nt] = __builtin_amdgcn_mfma_f32_16x16x32_bf16(af, bw[c * 4 + nt], acc3[nt], 0, 0, 0);
    }
    float part[4] = {0.0f, 0.0f, 0.0f, 0.0f};
    {
        const f32x4 w4 = *(const f32x4*)&sBias[192 + lr * 4];
        #pragma unroll
        for (int nt = 0; nt < 4; ++nt) {
            #pragma unroll
            for (int i = 0; i < 4; ++i) part[i] += silu_f(acc3[nt][i]) * w4[nt];
        }
    }
    #pragma unroll
    for (int m = 1; m <= 8; m <<= 1) {
        #pragma unroll
        for (int i = 0; i < 4; ++i) part[i] += __shfl_xor(part[i], m, 64);
    }
    if (lr == 0) {
        #pragma unroll
        for (int i = 0; i < 4; ++i) {
            const int slot = w * 16 + ks * 4 + i;
            const float dist = sGeom[slot * 4 + 3];
            const float g2 = fminf(fmaxf(2.0f * part[i], -30.0f), 30.0f);
            const float t = __expf(g2);
            const float th = (t - 1.0f) * rcp_fast(t + 1.0f);
            const float sc = th * 0.1f * rcp_fast(dist + EPS);
            sTrans[slot][0] = sGeom[slot * 4 + 0] * sc;
            sTrans[slot][1] = sGeom[slot * 4 + 1] * sc;
            sTrans[slot][2] = sGeom[slot * 4 + 2] * sc;
        }
    }

    // ---- m segmented reduce: wave reduces its OWN 16 rows (uniform branches),
    //      coalesced f32 atomics (64 consecutive floats per burst) ----
    {
        const int baserow = w * 16;
        int run_node = sRow[baserow];
        float runsum = 0.0f;
        #pragma unroll
        for (int r = 0; r < 16; ++r) {
            const int n = sRow[baserow + r];
            const float v = bf2f((unsigned short)sA[(baserow + r) * FSTR + l]);
            if (n != run_node) {
                atomicAdd(&mf[(size_t)run_node * 64 + l], runsum);
                run_node = n;
                runsum = v;
            } else {
                runsum += v;
            }
        }
        atomicAdd(&mf[(size_t)run_node * 64 + l], runsum);
    }

    // ---- trans segmented reduce: wave-local walkers (no block barrier) ----
    // sTrans written by this wave's lr==0 lanes; same-wave LDS is in-order,
    // fences stop compiler reordering (guide rule #18).
    __builtin_amdgcn_wave_barrier();
    asm volatile("s_waitcnt lgkmcnt(0)");
    __builtin_amdgcn_sched_barrier(0);
    if (l < 16) {
        const int s = w * 16 + l;
        const int n = sRow[s];
        if (l == 0 || sRow[s - 1] != n) {
            float sx = 0.0f, sy = 0.0f, sz = 0.0f;
            int j = s;
            const int jend = w * 16 + 16;
            while (j < jend && sRow[j] == n) {
                sx += sTrans[j][0];
                sy += sTrans[j][1];
                sz += sTrans[j][2];
                ++j;
            }
            atomicAdd(&xagg[n * 4 + 0], sx);
            atomicAdd(&xagg[n * 4 + 1], sy);
            atomicAdd(&xagg[n * 4 + 2], sz);
        }
    }
}

// ---------------- MFMA node kernel: MLP + residual + LayerNorm + x finalize --

#define NSTR 136   // 128 + 8 pad

__global__ __launch_bounds__(256) void node_mfma_kernel(
    const unsigned short* __restrict__ hbf, const float* __restrict__ mf,
    const int* __restrict__ counts,
    const unsigned short* __restrict__ Wn1p, const unsigned short* __restrict__ Wn2p,
    const float* __restrict__ Bn1, const float* __restrict__ Bn2,
    const float* __restrict__ ln_g, const float* __restrict__ ln_b,
    const float* __restrict__ x, const float* __restrict__ xagg,
    float* __restrict__ h_out, float* __restrict__ x_out)
{
    __shared__ short sA[64 * NSTR];   // 17408 B
    __shared__ float sBias[256];      // Bn1 | Bn2 | g | b

    const int tid = threadIdx.x;
    const int n0 = blockIdx.x * 64;

    if (tid < 64) {
        sBias[tid]       = Bn1[tid];
        sBias[64 + tid]  = Bn2[tid];
        sBias[128 + tid] = ln_g[tid];
        sBias[192 + tid] = ln_b[tid];
    }
    {
        const int s = tid >> 2, q = tid & 3;
        const int node = n0 + s;
        const int n = (node < NN) ? node : (NN - 1);
        const uint4* hr = (const uint4*)(hbf + (size_t)n * 64);
        *(uint4*)&sA[s * NSTR + q * 16]     = hr[q * 2];
        *(uint4*)&sA[s * NSTR + q * 16 + 8] = hr[q * 2 + 1];
        // m_i = mf / (count + EPS), f32 -> bf16
        const float inv = rcp_fast((float)counts[n] + EPS);
        const float4* mr = (const float4*)(mf + (size_t)n * 64) + q * 4;
        #pragma unroll
        for (int c2 = 0; c2 < 2; ++c2) {
            const float4 a = mr[c2 * 2], b = mr[c2 * 2 + 1];
            uint4 u;
            u.x = pk2_hw(a.x * inv, a.y * inv); u.y = pk2_hw(a.z * inv, a.w * inv);
            u.z = pk2_hw(b.x * inv, b.y * inv); u.w = pk2_hw(b.z * inv, b.w * inv);
            *(uint4*)&sA[s * NSTR + 64 + q * 16 + c2 * 8] = u;
        }
    }
    __syncthreads();

    const int w = tid >> 6, l = tid & 63;
    const int lr = l & 15;
    const int ks = l >> 4;
    const short* myA = &sA[(w * 16 + lr) * NSTR];

    // ---- node layer 1: [16,128] @ [128,64] ----
    f32x4 acc[4];
    {
        const f32x4 b4 = *(const f32x4*)&sBias[lr * 4];
        #pragma unroll
        for (int nt = 0; nt < 4; ++nt)
            acc[nt] = (f32x4){b4[nt], b4[nt], b4[nt], b4[nt]};
    }
    #pragma unroll
    for (int c = 0; c < 4; ++c) {
        const bf16x8 af = *(const bf16x8*)&myA[c * 32 + ks * 8];
        #pragma unroll
        for (int nt = 0; nt < 4; ++nt) {
            const bf16x8 bf = *(const bf16x8*)&Wn1p[((c * 4 + nt) * 64 + l) * 8];
            acc[nt] = __builtin_amdgcn_mfma_f32_16x16x32_bf16(af, bf, acc[nt], 0, 0, 0);
        }
    }
    // silu -> cols 64..127 (channel-perm packed writes)
    {
        short* pw = &sA[(w * 16 + ks * 4) * NSTR + 64 + lr * 4];
        #pragma unroll
        for (int i = 0; i < 4; ++i) {
            uint2 u;
            u.x = pk2_hw(silu_f(acc[0][i]), silu_f(acc[1][i]));
            u.y = pk2_hw(silu_f(acc[2][i]), silu_f(acc[3][i]));
            *(uint2*)&pw[i * NSTR] = u;
        }
    }

    // ---- node layer 2: [16,64] @ [64,64] ----
    f32x4 acc2[4];
    {
        const f32x4 b4 = *(const f32x4*)&sBias[64 + lr * 4];
        #pragma unroll
        for (int nt = 0; nt < 4; ++nt)
            acc2[nt] = (f32x4){b4[nt], b4[nt], b4[nt], b4[nt]};
    }
    #pragma unroll
    for (int c = 0; c < 2; ++c) {
        const bf16x8 af = *(const bf16x8*)&myA[64 + c * 32 + ks * 8];
        #pragma unroll
        for (int nt = 0; nt < 4; ++nt) {
            const bf16x8 bf = *(const bf16x8*)&Wn2p[((c * 4 + nt) * 64 + l) * 8];
            acc2[nt] = __builtin_amdgcn_mfma_f32_16x16x32_bf16(af, bf, acc2[nt], 0, 0, 0);
        }
    }

    // residual: thread's 4 nt channels are contiguous (lr*4..+3) -> b64 read
    float a2[4][4];
    #pragma unroll
    for (int i = 0; i < 4; ++i) {
        const uint2 hres = *(const uint2*)&sA[(w * 16 + ks * 4 + i) * NSTR + lr * 4];
        a2[0][i] = acc2[0][i] + bf2f((unsigned short)(hres.x & 0xffffu));
        a2[1][i] = acc2[1][i] + bf2f((unsigned short)(hres.x >> 16));
        a2[2][i] = acc2[2][i] + bf2f((unsigned short)(hres.y & 0xffffu));
        a2[3][i] = acc2[3][i] + bf2f((unsigned short)(hres.y >> 16));
    }

    float su[4];
    #pragma unroll
    for (int i = 0; i < 4; ++i)
        su[i] = a2[0][i] + a2[1][i] + a2[2][i] + a2[3][i];
    #pragma unroll
    for (int m = 1; m <= 8; m <<= 1)
        #pragma unroll
        for (int i = 0; i < 4; ++i) su[i] += __shfl_xor(su[i], m, 64);
    float mu[4];
    #pragma unroll
    for (int i = 0; i < 4; ++i) mu[i] = su[i] * (1.0f / 64.0f);

    float sv[4];
    #pragma unroll
    for (int i = 0; i < 4; ++i) {
        float s = 0.0f;
        #pragma unroll
        for (int nt = 0; nt < 4; ++nt) {
            const float d = a2[nt][i] - mu[i];
            s += d * d;
        }
        sv[i] = s;
    }
    #pragma unroll
    for (int m = 1; m <= 8; m <<= 1)
        #pragma unroll
        for (int i = 0; i < 4; ++i) sv[i] += __shfl_xor(sv[i], m, 64);

    {
        const f32x4 g4 = *(const f32x4*)&sBias[128 + lr * 4];
        const f32x4 b4 = *(const f32x4*)&sBias[192 + lr * 4];
        #pragma unroll
        for (int i = 0; i < 4; ++i) {
            const float rstd = rsqrtf(sv[i] * (1.0f / 64.0f) + LN_EPS);
            const int node = n0 + w * 16 + ks * 4 + i;
            if (node < NN) {
                float4 o;
                o.x = (a2[0][i] - mu[i]) * rstd * g4[0] + b4[0];
                o.y = (a2[1][i] - mu[i]) * rstd * g4[1] + b4[1];
                o.z = (a2[2][i] - mu[i]) * rstd * g4[2] + b4[2];
                o.w = (a2[3][i] - mu[i]) * rstd * g4[3] + b4[3];
                *(float4*)&h_out[(size_t)node * 64 + lr * 4] = o;
            }
        }
    }

    // ---- fused x finalize: one thread per node ----
    if (tid < 64) {
        const int n = n0 + tid;
        if (n < NN) {
            const float inv = rcp_fast((float)counts[n] + EPS);
            x_out[(size_t)n * 3 + 0] = x[(size_t)n * 3 + 0] + xagg[n * 4 + 0] * inv;
            x_out[(size_t)n * 3 + 1] = x[(size_t)n * 3 + 1] + xagg[n * 4 + 1] * inv;
            x_out[(size_t)n * 3 + 2] = x[(size_t)n * 3 + 2] + xagg[n * 4 + 2] * inv;
        }
    }
}

// ---------------- fallback (atomic path, minimal ws) ----------------

__global__ __launch_bounds__(64) void edge_atomic_kernel(
    const float* __restrict__ h, const float* __restrict__ x,
    const int* __restrict__ ei, const float* __restrict__ ea,
    const float* __restrict__ W1, const float* __restrict__ B1,
    const float* __restrict__ W2, const float* __restrict__ B2,
    const float* __restrict__ Wc1, const float* __restrict__ Bc1,
    const float* __restrict__ Wc2,
    float* __restrict__ m_acc, float* __restrict__ xagg)
{
    __shared__ float lds[64 * 64];
    const int lane = threadIdx.x;
    const int e = blockIdx.x * 64 + lane;

    const int row = ei[e];
    const int col = ei[NE + e];

    const float dx = x[row * 3 + 0] - x[col * 3 + 0];
    const float dy = x[row * 3 + 1] - x[col * 3 + 1];
    const float dz = x[row * 3 + 2] - x[col * 3 + 2];
    const float dist_sq = dx * dx + dy * dy + dz * dz;
    const float dist = sqrtf(dist_sq + EPS);
    const float logd = log1pf(dist_sq);

    float a1[64];
    #pragma unroll
    for (int j = 0; j < 64; ++j) a1[j] = B1[j];
    const float4* hr4 = (const float4*)(h + (size_t)row * 64);
    for (int k4 = 0; k4 < 16; ++k4) {
        const float4 v4 = hr4[k4];
        #pragma unroll
        for (int c = 0; c < 4; ++c) {
            const float v = (c == 0) ? v4.x : (c == 1) ? v4.y : (c == 2) ? v4.z : v4.w;
            const float* w = W1 + (k4 * 4 + c) * 64;
            #pragma unroll
            for (int j = 0; j < 64; ++j) a1[j] = fmaf(v, w[j], a1[j]);
        }
    }
    const float4* hc4 = (const float4*)(h + (size_t)col * 64);
    for (int k4 = 0; k4 < 16; ++k4) {
        const float4 v4 = hc4[k4];
        #pragma unroll
        for (int c = 0; c < 4; ++c) {
            const float v = (c == 0) ? v4.x : (c == 1) ? v4.y : (c == 2) ? v4.z : v4.w;
            const float* w = W1 + (64 + k4 * 4 + c) * 64;
            #pragma unroll
            for (int j = 0; j < 64; ++j) a1[j] = fmaf(v, w[j], a1[j]);
        }
    }
    {
        const float* w = W1 + 128 * 64;
        #pragma unroll
        for (int j = 0; j < 64; ++j) a1[j] = fmaf(logd, w[j], a1[j]);
    }
    const float4* ea4 = (const float4*)(ea + (size_t)e * 16);
    for (int k4 = 0; k4 < 4; ++k4) {
        const float4 v4 = ea4[k4];
        #pragma unroll
        for (int c = 0; c < 4; ++c) {
            const float v = (c == 0) ? v4.x : (c == 1) ? v4.y : (c == 2) ? v4.z : v4.w;
            const float* w = W1 + (129 + k4 * 4 + c) * 64;
            #pragma unroll
            for (int j = 0; j < 64; ++j) a1[j] = fmaf(v, w[j], a1[j]);
        }
    }

    #pragma unroll
    for (int j = 0; j < 64; ++j) lds[j * 64 + lane] = silu_f(a1[j]);

    float a2[64];
    #pragma unroll
    for (int j = 0; j < 64; ++j) a2[j] = B2[j];
    for (int k = 0; k < 64; ++k) {
        const float v = lds[k * 64 + lane];
        const float* w = W2 + k * 64;
        #pragma unroll
        for (int j = 0; j < 64; ++j) a2[j] = fmaf(v, w[j], a2[j]);
    }

    float* mrow = m_acc + (size_t)row * 64;
    #pragma unroll
    for (int j = 0; j < 64; ++j) {
        const float mj = silu_f(a2[j]);
        lds[j * 64 + lane] = mj;
        atomicAdd(mrow + j, mj);
    }

    float t[64];
    #pragma unroll
    for (int j = 0; j < 64; ++j) t[j] = Bc1[j];
    for (int k = 0; k < 64; ++k) {
        const float v = lds[k * 64 + lane];
        const float* w = Wc1 + k * 64;
        #pragma unroll
        for (int j = 0; j < 64; ++j) t[j] = fmaf(v, w[j], t[j]);
    }
    float g = 0.0f;
    #pragma unroll
    for (int j = 0; j < 64; ++j) g += silu_f(t[j]) * Wc2[j];

    const float s = tanhf(g) * 0.1f / (dist + EPS);
    atomicAdd(&xagg[row * 4 + 0], dx * s);
    atomicAdd(&xagg[row * 4 + 1], dy * s);
    atomicAdd(&xagg[row * 4 + 2], dz * s);
    atomicAdd(&xagg[row * 4 + 3], 1.0f);
}

__global__ __launch_bounds__(64) void node_csr_kernel(
    const float* __restrict__ h,
    const float* __restrict__ m_i,
    const float* __restrict__ Wn1, const float* __restrict__ Bn1,
    const float* __restrict__ Wn2, const float* __restrict__ Bn2,
    const float* __restrict__ ln_g, const float* __restrict__ ln_b,
    float* __restrict__ h_out)
{
    __shared__ float lds[64 * 64];
    const int lane = threadIdx.x;
    const int node = blockIdx.x * 64 + lane;
    const bool act = node < NN;
    const int n = act ? node : 0;

    float a1[64];
    #pragma unroll
    for (int j = 0; j < 64; ++j) a1[j] = Bn1[j];

    const float* hr = h + (size_t)n * 64;
    const float4* hr4 = (const float4*)hr;
    for (int k4 = 0; k4 < 16; ++k4) {
        const float4 v4 = hr4[k4];
        #pragma unroll
        for (int c = 0; c < 4; ++c) {
            const float v = (c == 0) ? v4.x : (c == 1) ? v4.y : (c == 2) ? v4.z : v4.w;
            const float* w = Wn1 + (k4 * 4 + c) * 64;
            #pragma unroll
            for (int j = 0; j < 64; ++j) a1[j] = fmaf(v, w[j], a1[j]);
        }
    }
    const float4* mr4 = (const float4*)(m_i + (size_t)n * 64);
    for (int k4 = 0; k4 < 16; ++k4) {
        const float4 v4 = mr4[k4];
        #pragma unroll
        for (int c = 0; c < 4; ++c) {
            const float v = (c == 0) ? v4.x : (c == 1) ? v4.y : (c == 2) ? v4.z : v4.w;
            const float* w = Wn1 + (64 + k4 * 4 + c) * 64;
            #pragma unroll
            for (int j = 0; j < 64; ++j) a1[j] = fmaf(v, w[j], a1[j]);
        }
    }

    #pragma unroll
    for (int j = 0; j < 64; ++j) lds[j * 64 + lane] = silu_f(a1[j]);

    float a2[64];
    #pragma unroll
    for (int j = 0; j < 64; ++j) a2[j] = Bn2[j];
    for (int k = 0; k < 64; ++k) {
        const float v = lds[k * 64 + lane];
        const float* w = Wn2 + k * 64;
        #pragma unroll
        for (int j = 0; j < 64; ++j) a2[j] = fmaf(v, w[j], a2[j]);
    }

    float mu = 0.0f;
    #pragma unroll
    for (int j = 0; j < 64; ++j) { a2[j] += hr[j]; mu += a2[j]; }
    mu *= (1.0f / 64.0f);
    float var = 0.0f;
    #pragma unroll
    for (int j = 0; j < 64; ++j) { const float d = a2[j] - mu; var += d * d; }
    var *= (1.0f / 64.0f);
    const float rstd = rsqrtf(var + LN_EPS);

    if (act) {
        #pragma unroll
        for (int j = 0; j < 64; ++j)
            h_out[(size_t)n * 64 + j] = (a2[j] - mu) * rstd * ln_g[j] + ln_b[j];
    }
}

__global__ void x_atomic_kernel(const float* __restrict__ x, const float* __restrict__ xagg,
                                float* __restrict__ x_out)
{
    const int i = blockIdx.x * 256 + threadIdx.x;
    if (i >= NN) return;
    const float inv_cnt = 1.0f / (xagg[i * 4 + 3] + EPS);
    #pragma unroll
    for (int c = 0; c < 3; ++c)
        x_out[(size_t)i * 3 + c] = x[(size_t)i * 3 + c] + xagg[i * 4 + c] * inv_cnt;
}

__global__ void div_m_kernel(float* __restrict__ m_acc, const float* __restrict__ xagg) {
    const int i = blockIdx.x * 256 + threadIdx.x;
    if (i >= NN * 64) return;
    m_acc[i] /= (xagg[(i >> 6) * 4 + 3] + EPS);
}

// ---------------- launch ----------------

extern "C" void kernel_launch(void* const* d_in, const int* in_sizes, int n_in,
                              void* d_out, int out_size, void* d_ws, size_t ws_size,
                              hipStream_t stream)
{
    const float* h   = (const float*)d_in[0];
    const float* x   = (const float*)d_in[1];
    const int*   ei  = (const int*)d_in[2];
    const float* ea  = (const float*)d_in[3];
    const float* W1  = (const float*)d_in[4];
    const float* B1  = (const float*)d_in[5];
    const float* W2  = (const float*)d_in[6];
    const float* B2  = (const float*)d_in[7];
    const float* Wn1 = (const float*)d_in[8];
    const float* Bn1 = (const float*)d_in[9];
    const float* Wn2 = (const float*)d_in[10];
    const float* Bn2 = (const float*)d_in[11];
    const float* Wc1 = (const float*)d_in[12];
    const float* Bc1 = (const float*)d_in[13];
    const float* Wc2 = (const float*)d_in[14];
    const float* lng = (const float*)d_in[15];
    const float* lnb = (const float*)d_in[16];

    float* out   = (float*)d_out;
    float* x_out = out + (size_t)NN * 64;

    size_t off = 0;
    auto take = [&](size_t bytes) { size_t p = off; off = (off + bytes + 255) & ~(size_t)255; return p; };
    char* ws = (char*)d_ws;
    const size_t o_quads  = take((size_t)NE * 16);         // int4 {eid,row,col,-}
    const size_t o_counts = take((size_t)NN * 4);
    const size_t o_rank   = take((size_t)NE * 4);          // within-node rank per edge
    const size_t o_offs   = take((size_t)(NN + 1) * 4);
    const size_t o_bsum   = take((size_t)1024 * 4);
    const size_t o_hbf    = take((size_t)NN * 64 * 2);     // bf16 h
    const size_t o_mf     = take((size_t)NN * 64 * 4);     // f32 m sum accumulator
    const size_t o_xagg   = take((size_t)NN * 4 * 4);      // f32 x aggregate
    const size_t o_w1p    = take((size_t)10240 * 2);
    const size_t o_w2p    = take((size_t)4096 * 2);
    const size_t o_wc1p   = take((size_t)4096 * 2);
    const size_t o_wn1p   = take((size_t)8192 * 2);
    const size_t o_wn2p   = take((size_t)4096 * 2);
    const size_t need = off;

    if (ws_size >= need) {
        int4*  quads  = (int4*)(ws + o_quads);
        int*   counts = (int*)(ws + o_counts);
        int*   rank   = (int*)(ws + o_rank);
        int*   offs   = (int*)(ws + o_offs);
        int*   bsum   = (int*)(ws + o_bsum);
        unsigned short* hbf   = (unsigned short*)(ws + o_hbf);
        float* mf     = (float*)(ws + o_mf);
        float* xagg   = (float*)(ws + o_xagg);
        unsigned short* W1p   = (unsigned short*)(ws + o_w1p);
        unsigned short* W2p   = (unsigned short*)(ws + o_w2p);
        unsigned short* Wc1p  = (unsigned short*)(ws + o_wc1p);
        unsigned short* Wn1p  = (unsigned short*)(ws + o_wn1p);
        unsigned short* Wn2p  = (unsigned short*)(ws + o_wn2p);

        hipMemsetAsync(counts, 0, (size_t)NN * 4, stream);
        hipMemsetAsync(mf, 0, (size_t)NN * 64 * 4, stream);
        hipMemsetAsync(xagg, 0, (size_t)NN * 4 * 4, stream);

        prep_count_kernel<<<HB_BLOCKS + PW_BLOCKS + CNT_BLOCKS, 256, 0, stream>>>(
            h, W1, W2, Wc1, Wn1, Wn2, ei,
            hbf, W1p, W2p, Wc1p, Wn1p, Wn2p, counts, rank);

        const int nblk = (NN + SCAN_B - 1) / SCAN_B;
        scan1_kernel<<<nblk, SCAN_B, 0, stream>>>(counts, offs, bsum);
        scan2_kernel<<<1, SCAN_B, 0, stream>>>(bsum, nblk);
        scatter_kernel<<<(NE + 255) / 256, 256, 0, stream>>>(ei, offs, bsum, rank, quads);

        edge_mfma_kernel<<<NE / 128, 512, 0, stream>>>(hbf, x, ea, W1p, W2p, Wc1p,
                                                       B1, B2, Bc1, Wc2, quads,
                                                       mf, xagg);
        node_mfma_kernel<<<(NN + 63) / 64, 256, 0, stream>>>(hbf, mf, counts, Wn1p, Wn2p,
                                                             Bn1, Bn2, lng, lnb,
                                                             x, xagg, out, x_out);
    } else {
        float* m_acc = out;
        float* xagg  = (float*)d_ws;
        hipMemsetAsync(m_acc, 0, (size_t)NN * 64 * 4, stream);
        hipMemsetAsync(xagg, 0, (size_t)NN * 4 * 4, stream);
        edge_atomic_kernel<<<NE / 64, 64, 0, stream>>>(h, x, ei, ea, W1, B1, W2, B2,
                                                       Wc1, Bc1, Wc2, m_acc, xagg);
        div_m_kernel<<<(NN * 64 + 255) / 256, 256, 0, stream>>>(m_acc, xagg);
        node_csr_kernel<<<(NN + 63) / 64, 64, 0, stream>>>(h, m_acc, Wn1, Bn1, Wn2, Bn2,
                                                           lng, lnb, m_acc);
        x_atomic_kernel<<<(NN + 255) / 256, 256, 0, stream>>>(x, xagg, m_acc + (size_t)NN * 64);
    }
}

// Round 11
// 349.486 us; speedup vs baseline: 1.0633x; 1.0349x over previous
//
#include <hip/hip_runtime.h>
#include <hip/hip_bf16.h>
#include <math.h>

#define NN 100000
#define NE 1600000

constexpr float EPS = 1e-8f;
constexpr float LN_EPS = 1e-5f;

typedef short bf16x8 __attribute__((ext_vector_type(8)));
typedef float f32x4 __attribute__((ext_vector_type(4)));

__device__ __forceinline__ float rcp_fast(float v) {
    return __builtin_amdgcn_rcpf(v);
}
__device__ __forceinline__ float silu_f(float v) {
    return v * rcp_fast(1.0f + __expf(-v));
}
__device__ __forceinline__ short f2bf_hw(float v) {
    union { __hip_bfloat16 b; short s; } u;
    u.b = __float2bfloat16(v);
    return u.s;
}
__device__ __forceinline__ unsigned int pk2_hw(float lo, float hi) {
    union { __hip_bfloat162 b2; unsigned int u; } u;
    u.b2 = __float22bfloat162_rn(make_float2(lo, hi));
    return u.u;
}
__device__ __forceinline__ float bf2f(unsigned short s) {
    return __uint_as_float(((unsigned int)s) << 16);
}

// ---------------- fused prep: bf16 h + frag-packed weights + count+rank ------
// frag order: elem ((c*4+nt)*64 + l)*8 + j  ==  W[k = c*32+(l>>4)*8+j][n]
// OUTPUT-CHANNEL PERM: n = (l&15)*4 + nt
// INTERLEAVE: h-convert blocks (even) and count-atomic blocks (odd) co-run so
// the latency-bound atomic pass hides the streaming pass (makespan = max not sum).

#define HB_BLOCKS 6250      // NN*64/4/256
#define PW_BLOCKS 120
#define CNT_BLOCKS 6250     // NE/256  (== HB_BLOCKS, exact parity pairing)

__global__ void prep_count_kernel(const float* __restrict__ h,
                            const float* __restrict__ W1, const float* __restrict__ W2,
                            const float* __restrict__ Wc1,
                            const float* __restrict__ Wn1, const float* __restrict__ Wn2,
                            const int* __restrict__ ei,
                            unsigned short* __restrict__ hbf,
                            unsigned short* __restrict__ W1p, unsigned short* __restrict__ W2p,
                            unsigned short* __restrict__ Wc1p,
                            unsigned short* __restrict__ Wn1p, unsigned short* __restrict__ Wn2p,
                            int* __restrict__ counts, int* __restrict__ rank)
{
    const int b = blockIdx.x;
    if (b < HB_BLOCKS + CNT_BLOCKS) {
        if (b & 1) {
            // count + rank in one atomic pass: returned old value IS the rank
            const int e = (b >> 1) * 256 + threadIdx.x;
            rank[e] = atomicAdd(&counts[ei[e]], 1);
        } else {
            const int i = (b >> 1) * 256 + threadIdx.x;     // 4 elems each
            const float4 v = ((const float4*)h)[i];
            uint2 u; u.x = pk2_hw(v.x, v.y); u.y = pk2_hw(v.z, v.w);
            ((uint2*)hbf)[i] = u;
        }
        return;
    }
    const int idx = (b - HB_BLOCKS - CNT_BLOCKS) * 256 + threadIdx.x;
    if (idx < 10240) {                           // W1: K=160 (145 real)
        const int j = idx & 7, l = (idx >> 3) & 63, nt = (idx >> 9) & 3, c = idx >> 11;
        const int k = c * 32 + (l >> 4) * 8 + j, n = (l & 15) * 4 + nt;
        W1p[idx] = (k < 145) ? (unsigned short)f2bf_hw(W1[k * 64 + n]) : (unsigned short)0;
    } else if (idx < 14336) {                    // W2: K=64
        const int t = idx - 10240;
        const int j = t & 7, l = (t >> 3) & 63, nt = (t >> 9) & 3, c = t >> 11;
        W2p[t] = (unsigned short)f2bf_hw(W2[(c * 32 + (l >> 4) * 8 + j) * 64 + (l & 15) * 4 + nt]);
    } else if (idx < 18432) {                    // Wc1: K=64
        const int t = idx - 14336;
        const int j = t & 7, l = (t >> 3) & 63, nt = (t >> 9) & 3, c = t >> 11;
        Wc1p[t] = (unsigned short)f2bf_hw(Wc1[(c * 32 + (l >> 4) * 8 + j) * 64 + (l & 15) * 4 + nt]);
    } else if (idx < 26624) {                    // Wn1: K=128
        const int t = idx - 18432;
        const int j = t & 7, l = (t >> 3) & 63, nt = (t >> 9) & 3, c = t >> 11;
        Wn1p[t] = (unsigned short)f2bf_hw(Wn1[(c * 32 + (l >> 4) * 8 + j) * 64 + (l & 15) * 4 + nt]);
    } else if (idx < 30720) {                    // Wn2: K=64
        const int t = idx - 26624;
        const int j = t & 7, l = (t >> 3) & 63, nt = (t >> 9) & 3, c = t >> 11;
        Wn2p[t] = (unsigned short)f2bf_hw(Wn2[(c * 32 + (l >> 4) * 8 + j) * 64 + (l & 15) * 4 + nt]);
    }
}

// ---------------- CSR build (scan + fused atomic-free scatter) ----------------

#define SCAN_B 512
__global__ __launch_bounds__(SCAN_B) void scan1_kernel(const int* __restrict__ counts,
                                                       int* __restrict__ offs,
                                                       int* __restrict__ bsum) {
    __shared__ int s[SCAN_B];
    const int tid = threadIdx.x;
    const int idx = blockIdx.x * SCAN_B + tid;
    const int v = (idx < NN) ? counts[idx] : 0;
    s[tid] = v;
    __syncthreads();
    for (int off = 1; off < SCAN_B; off <<= 1) {
        const int t = (tid >= off) ? s[tid - off] : 0;
        __syncthreads();
        s[tid] += t;
        __syncthreads();
    }
    if (idx < NN) offs[idx] = s[tid] - v;         // block-local exclusive
    if (tid == SCAN_B - 1) bsum[blockIdx.x] = s[tid];
}

__global__ __launch_bounds__(SCAN_B) void scan2_kernel(int* __restrict__ bsum, int nblk) {
    __shared__ int s[SCAN_B];
    const int tid = threadIdx.x;
    const int v = (tid < nblk) ? bsum[tid] : 0;
    s[tid] = v;
    __syncthreads();
    for (int off = 1; off < SCAN_B; off <<= 1) {
        const int t = (tid >= off) ? s[tid - off] : 0;
        __syncthreads();
        s[tid] += t;
        __syncthreads();
    }
    if (tid < nblk) bsum[tid] = s[tid] - v;       // exclusive
}

// scatter with fused block-sum add (no scan3 pass)
__global__ void scatter_kernel(const int* __restrict__ ei, const int* __restrict__ offs,
                               const int* __restrict__ bsum, const int* __restrict__ rank,
                               int4* __restrict__ quads) {
    const int e = blockIdx.x * 256 + threadIdx.x;
    if (e >= NE) return;
    const int r = ei[e];
    const int c = ei[NE + e];
    const int pos = offs[r] + bsum[r >> 9] + rank[e];   // no atomic
    quads[pos] = make_int4(e, r, c, 0);
}

// ---------------- MFMA edge kernel with in-kernel segmented reductions -------
// 512 thr = 8 waves, 128 CSR-ordered edges/block, 16 edges/wave.
// BOTH reductions are wave-local (uniform branches, partial sums + atomics);
// only ONE barrier in the whole kernel (after staging).

#define FSTR 168   // bf16 row stride (160 + 8 pad; 336B)

__global__ __launch_bounds__(512, 6) void edge_mfma_kernel(
    const unsigned short* __restrict__ hbf, const float* __restrict__ x,
    const float* __restrict__ ea,
    const unsigned short* __restrict__ W1p, const unsigned short* __restrict__ W2p,
    const unsigned short* __restrict__ Wc1p,
    const float* __restrict__ B1, const float* __restrict__ B2,
    const float* __restrict__ Bc1, const float* __restrict__ Wc2,
    const int4* __restrict__ quads,
    float* __restrict__ mf, float* __restrict__ xagg)
{
    __shared__ float sBias[256];        // B1 | B2 | Bc1 | Wc2
    __shared__ short sA[128 * FSTR];    // 43008 B
    __shared__ float sGeom[128 * 4];    // dx,dy,dz,dist
    __shared__ int   sRow[128];         // node id per slot
    __shared__ float sTrans[128][3];    // per-edge trans (wave-local use)

    const int tid = threadIdx.x;
    const int p0 = blockIdx.x * 128;

    if (tid < 64) {
        sBias[tid]       = B1[tid];
        sBias[64 + tid]  = B2[tid];
        sBias[128 + tid] = Bc1[tid];
        sBias[192 + tid] = Wc2[tid];
    }

    // stage features: 4 threads per edge slot
    {
        const int s = tid >> 2, q = tid & 3;
        const int4 pr = quads[p0 + s];
        const int eid = pr.x, row = pr.y, col = pr.z;

        const uint4* hr = (const uint4*)(hbf + (size_t)row * 64);
        *(uint4*)&sA[s * FSTR + q * 16]     = hr[q * 2];
        *(uint4*)&sA[s * FSTR + q * 16 + 8] = hr[q * 2 + 1];
        const uint4* hc = (const uint4*)(hbf + (size_t)col * 64);
        *(uint4*)&sA[s * FSTR + 64 + q * 16]     = hc[q * 2];
        *(uint4*)&sA[s * FSTR + 64 + q * 16 + 8] = hc[q * 2 + 1];

        const float4 e4 = ((const float4*)(ea + (size_t)eid * 16))[q];
        sA[s * FSTR + 129 + q * 4 + 0] = f2bf_hw(e4.x);
        sA[s * FSTR + 129 + q * 4 + 1] = f2bf_hw(e4.y);
        sA[s * FSTR + 129 + q * 4 + 2] = f2bf_hw(e4.z);
        sA[s * FSTR + 129 + q * 4 + 3] = f2bf_hw(e4.w);

        if (q == 0) {
            const float dx = x[row * 3 + 0] - x[col * 3 + 0];
            const float dy = x[row * 3 + 1] - x[col * 3 + 1];
            const float dz = x[row * 3 + 2] - x[col * 3 + 2];
            const float dist_sq = dx * dx + dy * dy + dz * dz;
            sGeom[s * 4 + 0] = dx;
            sGeom[s * 4 + 1] = dy;
            sGeom[s * 4 + 2] = dz;
            sGeom[s * 4 + 3] = sqrtf(dist_sq + EPS);
            sA[s * FSTR + 128] = f2bf_hw(log1pf(dist_sq));
        } else if (q == 1) {
            #pragma unroll
            for (int k = 145; k < 160; ++k) sA[s * FSTR + k] = 0;
        } else if (q == 2) {
            sRow[s] = row;
        }
    }
    __syncthreads();

    const int w = tid >> 6, l = tid & 63;
    const int lr = l & 15;
    const int ks = l >> 4;
    short* myA = &sA[(w * 16 + lr) * FSTR];

    // ---- msg layer 1: [16,160] @ [160,64], B via L1/L2 ----
    f32x4 acc[4];
    {
        const f32x4 b4 = *(const f32x4*)&sBias[lr * 4];
        #pragma unroll
        for (int nt = 0; nt < 4; ++nt)
            acc[nt] = (f32x4){b4[nt], b4[nt], b4[nt], b4[nt]};
    }
    #pragma unroll
    for (int c = 0; c < 5; ++c) {
        const bf16x8 af = *(const bf16x8*)&myA[c * 32 + ks * 8];
        #pragma unroll
        for (int nt = 0; nt < 4; ++nt) {
            const bf16x8 bf = *(const bf16x8*)&W1p[((c * 4 + nt) * 64 + l) * 8];
            acc[nt] = __builtin_amdgcn_mfma_f32_16x16x32_bf16(af, bf, acc[nt], 0, 0, 0);
        }
    }

    // prefetch W2 B-frags
    bf16x8 bw[8];
    #pragma unroll
    for (int c = 0; c < 2; ++c)
        #pragma unroll
        for (int nt = 0; nt < 4; ++nt)
            bw[c * 4 + nt] = *(const bf16x8*)&W2p[((c * 4 + nt) * 64 + l) * 8];

    {
        short* pw = &sA[(w * 16 + ks * 4) * FSTR + lr * 4];
        #pragma unroll
        for (int i = 0; i < 4; ++i) {
            uint2 u;
            u.x = pk2_hw(silu_f(acc[0][i]), silu_f(acc[1][i]));
            u.y = pk2_hw(silu_f(acc[2][i]), silu_f(acc[3][i]));
            *(uint2*)&pw[i * FSTR] = u;
        }
    }

    // ---- msg layer 2: [16,64] @ [64,64] ----
    f32x4 acc2[4];
    {
        const f32x4 b4 = *(const f32x4*)&sBias[64 + lr * 4];
        #pragma unroll
        for (int nt = 0; nt < 4; ++nt)
            acc2[nt] = (f32x4){b4[nt], b4[nt], b4[nt], b4[nt]};
    }
    #pragma unroll
    for (int c = 0; c < 2; ++c) {
        const bf16x8 af = *(const bf16x8*)&myA[c * 32 + ks * 8];
        #pragma unroll
        for (int nt = 0; nt < 4; ++nt)
            acc2[nt] = __builtin_amdgcn_mfma_f32_16x16x32_bf16(af, bw[c * 4 + nt], acc2[nt], 0, 0, 0);
    }

    // reload bw with Wc1 frags
    #pragma unroll
    for (int c = 0; c < 2; ++c)
        #pragma unroll
        for (int nt = 0; nt < 4; ++nt)
            bw[c * 4 + nt] = *(const bf16x8*)&Wc1p[((c * 4 + nt) * 64 + l) * 8];

    {
        short* pw = &sA[(w * 16 + ks * 4) * FSTR + lr * 4];
        #pragma unroll
        for (int i = 0; i < 4; ++i) {
            uint2 u;
            u.x = pk2_hw(silu_f(acc2[0][i]), silu_f(acc2[1][i]));
            u.y = pk2_hw(silu_f(acc2[2][i]), silu_f(acc2[3][i]));
            *(uint2*)&pw[i * FSTR] = u;
        }
    }

    // ---- coord layer 1: [16,64] @ [64,64], input = m (cols 0..63) ----
    f32x4 acc3[4];
    {
        const f32x4 b4 = *(const f32x4*)&sBias[128 + lr * 4];
        #pragma unroll
        for (int nt = 0; nt < 4; ++nt)
            acc3[nt] = (f32x4){b4[nt], b4[nt], b4[nt], b4[nt]};
    }
    #pragma unroll
    for (int c = 0; c < 2; ++c) {
        const bf16x8 af = *(const bf16x8*)&myA[c * 32 + ks * 8];
        #pragma unroll
        for (int nt = 0; nt < 4; ++nt)
            acc3[nt] = __builtin_amdgcn_mfma_f32_16x16x32_bf16(af, bw[c * 4 + nt], acc3[nt], 0, 0, 0);
    }
    float part[4] = {0.0f, 0.0f, 0.0f, 0.0f};
    {
        const f32x4 w4 = *(const f32x4*)&sBias[192 + lr * 4];
        #pragma unroll
        for (int nt = 0; nt < 4; ++nt) {
            #pragma unroll
            for (int i = 0; i < 4; ++i) part[i] += silu_f(acc3[nt][i]) * w4[nt];
        }
    }
    #pragma unroll
    for (int m = 1; m <= 8; m <<= 1) {
        #pragma unroll
        for (int i = 0; i < 4; ++i) part[i] += __shfl_xor(part[i], m, 64);
    }
    if (lr == 0) {
        #pragma unroll
        for (int i = 0; i < 4; ++i) {
            const int slot = w * 16 + ks * 4 + i;
            const float dist = sGeom[slot * 4 + 3];
            const float g2 = fminf(fmaxf(2.0f * part[i], -30.0f), 30.0f);
            const float t = __expf(g2);
            const float th = (t - 1.0f) * rcp_fast(t + 1.0f);
            const float sc = th * 0.1f * rcp_fast(dist + EPS);
            sTrans[slot][0] = sGeom[slot * 4 + 0] * sc;
            sTrans[slot][1] = sGeom[slot * 4 + 1] * sc;
            sTrans[slot][2] = sGeom[slot * 4 + 2] * sc;
        }
    }

    // ---- m segmented reduce: wave reduces its OWN 16 rows (uniform branches),
    //      coalesced f32 atomics (64 consecutive floats per burst) ----
    {
        const int baserow = w * 16;
        int run_node = sRow[baserow];
        float runsum = 0.0f;
        #pragma unroll
        for (int r = 0; r < 16; ++r) {
            const int n = sRow[baserow + r];
            const float v = bf2f((unsigned short)sA[(baserow + r) * FSTR + l]);
            if (n != run_node) {
                atomicAdd(&mf[(size_t)run_node * 64 + l], runsum);
                run_node = n;
                runsum = v;
            } else {
                runsum += v;
            }
        }
        atomicAdd(&mf[(size_t)run_node * 64 + l], runsum);
    }

    // ---- trans segmented reduce: wave-local walkers (no block barrier) ----
    __builtin_amdgcn_wave_barrier();
    asm volatile("s_waitcnt lgkmcnt(0)");
    __builtin_amdgcn_sched_barrier(0);
    if (l < 16) {
        const int s = w * 16 + l;
        const int n = sRow[s];
        if (l == 0 || sRow[s - 1] != n) {
            float sx = 0.0f, sy = 0.0f, sz = 0.0f;
            int j = s;
            const int jend = w * 16 + 16;
            while (j < jend && sRow[j] == n) {
                sx += sTrans[j][0];
                sy += sTrans[j][1];
                sz += sTrans[j][2];
                ++j;
            }
            atomicAdd(&xagg[n * 4 + 0], sx);
            atomicAdd(&xagg[n * 4 + 1], sy);
            atomicAdd(&xagg[n * 4 + 2], sz);
        }
    }
}

// ---------------- MFMA node kernel: MLP + residual + LayerNorm + x finalize --

#define NSTR 136   // 128 + 8 pad

__global__ __launch_bounds__(256) void node_mfma_kernel(
    const unsigned short* __restrict__ hbf, const float* __restrict__ mf,
    const int* __restrict__ counts,
    const unsigned short* __restrict__ Wn1p, const unsigned short* __restrict__ Wn2p,
    const float* __restrict__ Bn1, const float* __restrict__ Bn2,
    const float* __restrict__ ln_g, const float* __restrict__ ln_b,
    const float* __restrict__ x, const float* __restrict__ xagg,
    float* __restrict__ h_out, float* __restrict__ x_out)
{
    __shared__ short sA[64 * NSTR];   // 17408 B
    __shared__ float sBias[256];      // Bn1 | Bn2 | g | b

    const int tid = threadIdx.x;
    const int n0 = blockIdx.x * 64;

    if (tid < 64) {
        sBias[tid]       = Bn1[tid];
        sBias[64 + tid]  = Bn2[tid];
        sBias[128 + tid] = ln_g[tid];
        sBias[192 + tid] = ln_b[tid];
    }
    {
        const int s = tid >> 2, q = tid & 3;
        const int node = n0 + s;
        const int n = (node < NN) ? node : (NN - 1);
        const uint4* hr = (const uint4*)(hbf + (size_t)n * 64);
        *(uint4*)&sA[s * NSTR + q * 16]     = hr[q * 2];
        *(uint4*)&sA[s * NSTR + q * 16 + 8] = hr[q * 2 + 1];
        // m_i = mf / (count + EPS), f32 -> bf16
        const float inv = rcp_fast((float)counts[n] + EPS);
        const float4* mr = (const float4*)(mf + (size_t)n * 64) + q * 4;
        #pragma unroll
        for (int c2 = 0; c2 < 2; ++c2) {
            const float4 a = mr[c2 * 2], b = mr[c2 * 2 + 1];
            uint4 u;
            u.x = pk2_hw(a.x * inv, a.y * inv); u.y = pk2_hw(a.z * inv, a.w * inv);
            u.z = pk2_hw(b.x * inv, b.y * inv); u.w = pk2_hw(b.z * inv, b.w * inv);
            *(uint4*)&sA[s * NSTR + 64 + q * 16 + c2 * 8] = u;
        }
    }
    __syncthreads();

    const int w = tid >> 6, l = tid & 63;
    const int lr = l & 15;
    const int ks = l >> 4;
    const short* myA = &sA[(w * 16 + lr) * NSTR];

    // ---- node layer 1: [16,128] @ [128,64] ----
    f32x4 acc[4];
    {
        const f32x4 b4 = *(const f32x4*)&sBias[lr * 4];
        #pragma unroll
        for (int nt = 0; nt < 4; ++nt)
            acc[nt] = (f32x4){b4[nt], b4[nt], b4[nt], b4[nt]};
    }
    #pragma unroll
    for (int c = 0; c < 4; ++c) {
        const bf16x8 af = *(const bf16x8*)&myA[c * 32 + ks * 8];
        #pragma unroll
        for (int nt = 0; nt < 4; ++nt) {
            const bf16x8 bf = *(const bf16x8*)&Wn1p[((c * 4 + nt) * 64 + l) * 8];
            acc[nt] = __builtin_amdgcn_mfma_f32_16x16x32_bf16(af, bf, acc[nt], 0, 0, 0);
        }
    }
    // silu -> cols 64..127 (channel-perm packed writes)
    {
        short* pw = &sA[(w * 16 + ks * 4) * NSTR + 64 + lr * 4];
        #pragma unroll
        for (int i = 0; i < 4; ++i) {
            uint2 u;
            u.x = pk2_hw(silu_f(acc[0][i]), silu_f(acc[1][i]));
            u.y = pk2_hw(silu_f(acc[2][i]), silu_f(acc[3][i]));
            *(uint2*)&pw[i * NSTR] = u;
        }
    }

    // ---- node layer 2: [16,64] @ [64,64] ----
    f32x4 acc2[4];
    {
        const f32x4 b4 = *(const f32x4*)&sBias[64 + lr * 4];
        #pragma unroll
        for (int nt = 0; nt < 4; ++nt)
            acc2[nt] = (f32x4){b4[nt], b4[nt], b4[nt], b4[nt]};
    }
    #pragma unroll
    for (int c = 0; c < 2; ++c) {
        const bf16x8 af = *(const bf16x8*)&myA[64 + c * 32 + ks * 8];
        #pragma unroll
        for (int nt = 0; nt < 4; ++nt) {
            const bf16x8 bf = *(const bf16x8*)&Wn2p[((c * 4 + nt) * 64 + l) * 8];
            acc2[nt] = __builtin_amdgcn_mfma_f32_16x16x32_bf16(af, bf, acc2[nt], 0, 0, 0);
        }
    }

    // residual: thread's 4 nt channels are contiguous (lr*4..+3) -> b64 read
    float a2[4][4];
    #pragma unroll
    for (int i = 0; i < 4; ++i) {
        const uint2 hres = *(const uint2*)&sA[(w * 16 + ks * 4 + i) * NSTR + lr * 4];
        a2[0][i] = acc2[0][i] + bf2f((unsigned short)(hres.x & 0xffffu));
        a2[1][i] = acc2[1][i] + bf2f((unsigned short)(hres.x >> 16));
        a2[2][i] = acc2[2][i] + bf2f((unsigned short)(hres.y & 0xffffu));
        a2[3][i] = acc2[3][i] + bf2f((unsigned short)(hres.y >> 16));
    }

    float su[4];
    #pragma unroll
    for (int i = 0; i < 4; ++i)
        su[i] = a2[0][i] + a2[1][i] + a2[2][i] + a2[3][i];
    #pragma unroll
    for (int m = 1; m <= 8; m <<= 1)
        #pragma unroll
        for (int i = 0; i < 4; ++i) su[i] += __shfl_xor(su[i], m, 64);
    float mu[4];
    #pragma unroll
    for (int i = 0; i < 4; ++i) mu[i] = su[i] * (1.0f / 64.0f);

    float sv[4];
    #pragma unroll
    for (int i = 0; i < 4; ++i) {
        float s = 0.0f;
        #pragma unroll
        for (int nt = 0; nt < 4; ++nt) {
            const float d = a2[nt][i] - mu[i];
            s += d * d;
        }
        sv[i] = s;
    }
    #pragma unroll
    for (int m = 1; m <= 8; m <<= 1)
        #pragma unroll
        for (int i = 0; i < 4; ++i) sv[i] += __shfl_xor(sv[i], m, 64);

    {
        const f32x4 g4 = *(const f32x4*)&sBias[128 + lr * 4];
        const f32x4 b4 = *(const f32x4*)&sBias[192 + lr * 4];
        #pragma unroll
        for (int i = 0; i < 4; ++i) {
            const float rstd = rsqrtf(sv[i] * (1.0f / 64.0f) + LN_EPS);
            const int node = n0 + w * 16 + ks * 4 + i;
            if (node < NN) {
                float4 o;
                o.x = (a2[0][i] - mu[i]) * rstd * g4[0] + b4[0];
                o.y = (a2[1][i] - mu[i]) * rstd * g4[1] + b4[1];
                o.z = (a2[2][i] - mu[i]) * rstd * g4[2] + b4[2];
                o.w = (a2[3][i] - mu[i]) * rstd * g4[3] + b4[3];
                *(float4*)&h_out[(size_t)node * 64 + lr * 4] = o;
            }
        }
    }

    // ---- fused x finalize: one thread per node ----
    if (tid < 64) {
        const int n = n0 + tid;
        if (n < NN) {
            const float inv = rcp_fast((float)counts[n] + EPS);
            x_out[(size_t)n * 3 + 0] = x[(size_t)n * 3 + 0] + xagg[n * 4 + 0] * inv;
            x_out[(size_t)n * 3 + 1] = x[(size_t)n * 3 + 1] + xagg[n * 4 + 1] * inv;
            x_out[(size_t)n * 3 + 2] = x[(size_t)n * 3 + 2] + xagg[n * 4 + 2] * inv;
        }
    }
}

// ---------------- fallback (atomic path, minimal ws) ----------------

__global__ __launch_bounds__(64) void edge_atomic_kernel(
    const float* __restrict__ h, const float* __restrict__ x,
    const int* __restrict__ ei, const float* __restrict__ ea,
    const float* __restrict__ W1, const float* __restrict__ B1,
    const float* __restrict__ W2, const float* __restrict__ B2,
    const float* __restrict__ Wc1, const float* __restrict__ Bc1,
    const float* __restrict__ Wc2,
    float* __restrict__ m_acc, float* __restrict__ xagg)
{
    __shared__ float lds[64 * 64];
    const int lane = threadIdx.x;
    const int e = blockIdx.x * 64 + lane;

    const int row = ei[e];
    const int col = ei[NE + e];

    const float dx = x[row * 3 + 0] - x[col * 3 + 0];
    const float dy = x[row * 3 + 1] - x[col * 3 + 1];
    const float dz = x[row * 3 + 2] - x[col * 3 + 2];
    const float dist_sq = dx * dx + dy * dy + dz * dz;
    const float dist = sqrtf(dist_sq + EPS);
    const float logd = log1pf(dist_sq);

    float a1[64];
    #pragma unroll
    for (int j = 0; j < 64; ++j) a1[j] = B1[j];
    const float4* hr4 = (const float4*)(h + (size_t)row * 64);
    for (int k4 = 0; k4 < 16; ++k4) {
        const float4 v4 = hr4[k4];
        #pragma unroll
        for (int c = 0; c < 4; ++c) {
            const float v = (c == 0) ? v4.x : (c == 1) ? v4.y : (c == 2) ? v4.z : v4.w;
            const float* w = W1 + (k4 * 4 + c) * 64;
            #pragma unroll
            for (int j = 0; j < 64; ++j) a1[j] = fmaf(v, w[j], a1[j]);
        }
    }
    const float4* hc4 = (const float4*)(h + (size_t)col * 64);
    for (int k4 = 0; k4 < 16; ++k4) {
        const float4 v4 = hc4[k4];
        #pragma unroll
        for (int c = 0; c < 4; ++c) {
            const float v = (c == 0) ? v4.x : (c == 1) ? v4.y : (c == 2) ? v4.z : v4.w;
            const float* w = W1 + (64 + k4 * 4 + c) * 64;
            #pragma unroll
            for (int j = 0; j < 64; ++j) a1[j] = fmaf(v, w[j], a1[j]);
        }
    }
    {
        const float* w = W1 + 128 * 64;
        #pragma unroll
        for (int j = 0; j < 64; ++j) a1[j] = fmaf(logd, w[j], a1[j]);
    }
    const float4* ea4 = (const float4*)(ea + (size_t)e * 16);
    for (int k4 = 0; k4 < 4; ++k4) {
        const float4 v4 = ea4[k4];
        #pragma unroll
        for (int c = 0; c < 4; ++c) {
            const float v = (c == 0) ? v4.x : (c == 1) ? v4.y : (c == 2) ? v4.z : v4.w;
            const float* w = W1 + (129 + k4 * 4 + c) * 64;
            #pragma unroll
            for (int j = 0; j < 64; ++j) a1[j] = fmaf(v, w[j], a1[j]);
        }
    }

    #pragma unroll
    for (int j = 0; j < 64; ++j) lds[j * 64 + lane] = silu_f(a1[j]);

    float a2[64];
    #pragma unroll
    for (int j = 0; j < 64; ++j) a2[j] = B2[j];
    for (int k = 0; k < 64; ++k) {
        const float v = lds[k * 64 + lane];
        const float* w = W2 + k * 64;
        #pragma unroll
        for (int j = 0; j < 64; ++j) a2[j] = fmaf(v, w[j], a2[j]);
    }

    float* mrow = m_acc + (size_t)row * 64;
    #pragma unroll
    for (int j = 0; j < 64; ++j) {
        const float mj = silu_f(a2[j]);
        lds[j * 64 + lane] = mj;
        atomicAdd(mrow + j, mj);
    }

    float t[64];
    #pragma unroll
    for (int j = 0; j < 64; ++j) t[j] = Bc1[j];
    for (int k = 0; k < 64; ++k) {
        const float v = lds[k * 64 + lane];
        const float* w = Wc1 + k * 64;
        #pragma unroll
        for (int j = 0; j < 64; ++j) t[j] = fmaf(v, w[j], t[j]);
    }
    float g = 0.0f;
    #pragma unroll
    for (int j = 0; j < 64; ++j) g += silu_f(t[j]) * Wc2[j];

    const float s = tanhf(g) * 0.1f / (dist + EPS);
    atomicAdd(&xagg[row * 4 + 0], dx * s);
    atomicAdd(&xagg[row * 4 + 1], dy * s);
    atomicAdd(&xagg[row * 4 + 2], dz * s);
    atomicAdd(&xagg[row * 4 + 3], 1.0f);
}

__global__ __launch_bounds__(64) void node_csr_kernel(
    const float* __restrict__ h,
    const float* __restrict__ m_i,
    const float* __restrict__ Wn1, const float* __restrict__ Bn1,
    const float* __restrict__ Wn2, const float* __restrict__ Bn2,
    const float* __restrict__ ln_g, const float* __restrict__ ln_b,
    float* __restrict__ h_out)
{
    __shared__ float lds[64 * 64];
    const int lane = threadIdx.x;
    const int node = blockIdx.x * 64 + lane;
    const bool act = node < NN;
    const int n = act ? node : 0;

    float a1[64];
    #pragma unroll
    for (int j = 0; j < 64; ++j) a1[j] = Bn1[j];

    const float* hr = h + (size_t)n * 64;
    const float4* hr4 = (const float4*)hr;
    for (int k4 = 0; k4 < 16; ++k4) {
        const float4 v4 = hr4[k4];
        #pragma unroll
        for (int c = 0; c < 4; ++c) {
            const float v = (c == 0) ? v4.x : (c == 1) ? v4.y : (c == 2) ? v4.z : v4.w;
            const float* w = Wn1 + (k4 * 4 + c) * 64;
            #pragma unroll
            for (int j = 0; j < 64; ++j) a1[j] = fmaf(v, w[j], a1[j]);
        }
    }
    const float4* mr4 = (const float4*)(m_i + (size_t)n * 64);
    for (int k4 = 0; k4 < 16; ++k4) {
        const float4 v4 = mr4[k4];
        #pragma unroll
        for (int c = 0; c < 4; ++c) {
            const float v = (c == 0) ? v4.x : (c == 1) ? v4.y : (c == 2) ? v4.z : v4.w;
            const float* w = Wn1 + (64 + k4 * 4 + c) * 64;
            #pragma unroll
            for (int j = 0; j < 64; ++j) a1[j] = fmaf(v, w[j], a1[j]);
        }
    }

    #pragma unroll
    for (int j = 0; j < 64; ++j) lds[j * 64 + lane] = silu_f(a1[j]);

    float a2[64];
    #pragma unroll
    for (int j = 0; j < 64; ++j) a2[j] = Bn2[j];
    for (int k = 0; k < 64; ++k) {
        const float v = lds[k * 64 + lane];
        const float* w = Wn2 + k * 64;
        #pragma unroll
        for (int j = 0; j < 64; ++j) a2[j] = fmaf(v, w[j], a2[j]);
    }

    float mu = 0.0f;
    #pragma unroll
    for (int j = 0; j < 64; ++j) { a2[j] += hr[j]; mu += a2[j]; }
    mu *= (1.0f / 64.0f);
    float var = 0.0f;
    #pragma unroll
    for (int j = 0; j < 64; ++j) { const float d = a2[j] - mu; var += d * d; }
    var *= (1.0f / 64.0f);
    const float rstd = rsqrtf(var + LN_EPS);

    if (act) {
        #pragma unroll
        for (int j = 0; j < 64; ++j)
            h_out[(size_t)n * 64 + j] = (a2[j] - mu) * rstd * ln_g[j] + ln_b[j];
    }
}

__global__ void x_atomic_kernel(const float* __restrict__ x, const float* __restrict__ xagg,
                                float* __restrict__ x_out)
{
    const int i = blockIdx.x * 256 + threadIdx.x;
    if (i >= NN) return;
    const float inv_cnt = 1.0f / (xagg[i * 4 + 3] + EPS);
    #pragma unroll
    for (int c = 0; c < 3; ++c)
        x_out[(size_t)i * 3 + c] = x[(size_t)i * 3 + c] + xagg[i * 4 + c] * inv_cnt;
}

__global__ void div_m_kernel(float* __restrict__ m_acc, const float* __restrict__ xagg) {
    const int i = blockIdx.x * 256 + threadIdx.x;
    if (i >= NN * 64) return;
    m_acc[i] /= (xagg[(i >> 6) * 4 + 3] + EPS);
}

// ---------------- launch ----------------

extern "C" void kernel_launch(void* const* d_in, const int* in_sizes, int n_in,
                              void* d_out, int out_size, void* d_ws, size_t ws_size,
                              hipStream_t stream)
{
    const float* h   = (const float*)d_in[0];
    const float* x   = (const float*)d_in[1];
    const int*   ei  = (const int*)d_in[2];
    const float* ea  = (const float*)d_in[3];
    const float* W1  = (const float*)d_in[4];
    const float* B1  = (const float*)d_in[5];
    const float* W2  = (const float*)d_in[6];
    const float* B2  = (const float*)d_in[7];
    const float* Wn1 = (const float*)d_in[8];
    const float* Bn1 = (const float*)d_in[9];
    const float* Wn2 = (const float*)d_in[10];
    const float* Bn2 = (const float*)d_in[11];
    const float* Wc1 = (const float*)d_in[12];
    const float* Bc1 = (const float*)d_in[13];
    const float* Wc2 = (const float*)d_in[14];
    const float* lng = (const float*)d_in[15];
    const float* lnb = (const float*)d_in[16];

    float* out   = (float*)d_out;
    float* x_out = out + (size_t)NN * 64;

    size_t off = 0;
    auto take = [&](size_t bytes) { size_t p = off; off = (off + bytes + 255) & ~(size_t)255; return p; };
    char* ws = (char*)d_ws;
    const size_t o_quads  = take((size_t)NE * 16);         // int4 {eid,row,col,-}
    const size_t o_counts = take((size_t)NN * 4);
    const size_t o_rank   = take((size_t)NE * 4);          // within-node rank per edge
    const size_t o_offs   = take((size_t)(NN + 1) * 4);
    const size_t o_bsum   = take((size_t)1024 * 4);
    const size_t o_hbf    = take((size_t)NN * 64 * 2);     // bf16 h
    const size_t o_mf     = take((size_t)NN * 64 * 4);     // f32 m sum accumulator
    const size_t o_xagg   = take((size_t)NN * 4 * 4);      // f32 x aggregate
    const size_t o_w1p    = take((size_t)10240 * 2);
    const size_t o_w2p    = take((size_t)4096 * 2);
    const size_t o_wc1p   = take((size_t)4096 * 2);
    const size_t o_wn1p   = take((size_t)8192 * 2);
    const size_t o_wn2p   = take((size_t)4096 * 2);
    const size_t need = off;

    if (ws_size >= need) {
        int4*  quads  = (int4*)(ws + o_quads);
        int*   counts = (int*)(ws + o_counts);
        int*   rank   = (int*)(ws + o_rank);
        int*   offs   = (int*)(ws + o_offs);
        int*   bsum   = (int*)(ws + o_bsum);
        unsigned short* hbf   = (unsigned short*)(ws + o_hbf);
        float* mf     = (float*)(ws + o_mf);
        float* xagg   = (float*)(ws + o_xagg);
        unsigned short* W1p   = (unsigned short*)(ws + o_w1p);
        unsigned short* W2p   = (unsigned short*)(ws + o_w2p);
        unsigned short* Wc1p  = (unsigned short*)(ws + o_wc1p);
        unsigned short* Wn1p  = (unsigned short*)(ws + o_wn1p);
        unsigned short* Wn2p  = (unsigned short*)(ws + o_wn2p);

        hipMemsetAsync(counts, 0, (size_t)NN * 4, stream);
        hipMemsetAsync(mf, 0, (size_t)NN * 64 * 4, stream);
        hipMemsetAsync(xagg, 0, (size_t)NN * 4 * 4, stream);

        prep_count_kernel<<<HB_BLOCKS + CNT_BLOCKS + PW_BLOCKS, 256, 0, stream>>>(
            h, W1, W2, Wc1, Wn1, Wn2, ei,
            hbf, W1p, W2p, Wc1p, Wn1p, Wn2p, counts, rank);

        const int nblk = (NN + SCAN_B - 1) / SCAN_B;
        scan1_kernel<<<nblk, SCAN_B, 0, stream>>>(counts, offs, bsum);
        scan2_kernel<<<1, SCAN_B, 0, stream>>>(bsum, nblk);
        scatter_kernel<<<(NE + 255) / 256, 256, 0, stream>>>(ei, offs, bsum, rank, quads);

        edge_mfma_kernel<<<NE / 128, 512, 0, stream>>>(hbf, x, ea, W1p, W2p, Wc1p,
                                                       B1, B2, Bc1, Wc2, quads,
                                                       mf, xagg);
        node_mfma_kernel<<<(NN + 63) / 64, 256, 0, stream>>>(hbf, mf, counts, Wn1p, Wn2p,
                                                             Bn1, Bn2, lng, lnb,
                                                             x, xagg, out, x_out);
    } else {
        float* m_acc = out;
        float* xagg  = (float*)d_ws;
        hipMemsetAsync(m_acc, 0, (size_t)NN * 64 * 4, stream);
        hipMemsetAsync(xagg, 0, (size_t)NN * 4 * 4, stream);
        edge_atomic_kernel<<<NE / 64, 64, 0, stream>>>(h, x, ei, ea, W1, B1, W2, B2,
                                                       Wc1, Bc1, Wc2, m_acc, xagg);
        div_m_kernel<<<(NN * 64 + 255) / 256, 256, 0, stream>>>(m_acc, xagg);
        node_csr_kernel<<<(NN + 63) / 64, 64, 0, stream>>>(h, m_acc, Wn1, Bn1, Wn2, Bn2,
                                                           lng, lnb, m_acc);
        x_atomic_kernel<<<(NN + 255) / 256, 256, 0, stream>>>(x, xagg, m_acc + (size_t)NN * 64);
    }
}

// Round 12
// 349.254 us; speedup vs baseline: 1.0640x; 1.0007x over previous
//
#include <hip/hip_runtime.h>
#include <hip/hip_bf16.h>
#include <math.h>

#define NN 100000
#define NE 1600000

constexpr float EPS = 1e-8f;
constexpr float LN_EPS = 1e-5f;

typedef short bf16x8 __attribute__((ext_vector_type(8)));
typedef float f32x4 __attribute__((ext_vector_type(4)));

__device__ __forceinline__ float rcp_fast(float v) {
    return __builtin_amdgcn_rcpf(v);
}
__device__ __forceinline__ float silu_f(float v) {
    return v * rcp_fast(1.0f + __expf(-v));
}
__device__ __forceinline__ short f2bf_hw(float v) {
    union { __hip_bfloat16 b; short s; } u;
    u.b = __float2bfloat16(v);
    return u.s;
}
__device__ __forceinline__ unsigned int pk2_hw(float lo, float hi) {
    union { __hip_bfloat162 b2; unsigned int u; } u;
    u.b2 = __float22bfloat162_rn(make_float2(lo, hi));
    return u.u;
}
__device__ __forceinline__ float bf2f(unsigned short s) {
    return __uint_as_float(((unsigned int)s) << 16);
}

// ---------------- fused prep: bf16 h + bf16 ea + weights + count+rank + mf=0 -
// frag order: elem ((c*4+nt)*64 + l)*8 + j  ==  W[k = c*32+(l>>4)*8+j][n]
// OUTPUT-CHANNEL PERM: n = (l&15)*4 + nt
// sA k-layout (edge): 0..127 h_row|h_col, 128 logd, 129..131 zero,
//                     132..147 ea (8B-aligned), 148..159 zero.
// W1p rows remapped to match (k<129 -> W1[k]; 132..147 -> W1[k-3]; else 0).
// 3-way block interleave (h / ea / count) hides streaming under the atomic pass.

#define TRI_BLOCKS 18750    // 3 * 6250
#define PW_BLOCKS 120

__global__ void prep_count_kernel(const float* __restrict__ h,
                            const float* __restrict__ ea,
                            const float* __restrict__ W1, const float* __restrict__ W2,
                            const float* __restrict__ Wc1,
                            const float* __restrict__ Wn1, const float* __restrict__ Wn2,
                            const int* __restrict__ ei,
                            unsigned short* __restrict__ hbf,
                            unsigned short* __restrict__ eabf,
                            unsigned short* __restrict__ W1p, unsigned short* __restrict__ W2p,
                            unsigned short* __restrict__ Wc1p,
                            unsigned short* __restrict__ Wn1p, unsigned short* __restrict__ Wn2p,
                            int* __restrict__ counts, int* __restrict__ rank,
                            float* __restrict__ mf)
{
    const int b = blockIdx.x;
    if (b < TRI_BLOCKS) {
        const int sub = b / 3;
        const int kind = b % 3;
        if (kind == 0) {
            // h f32 -> bf16 (4 elems/thread) + zero one float4 of mf
            const int i = sub * 256 + threadIdx.x;
            const float4 v = ((const float4*)h)[i];
            uint2 u; u.x = pk2_hw(v.x, v.y); u.y = pk2_hw(v.z, v.w);
            ((uint2*)hbf)[i] = u;
            ((float4*)mf)[i] = make_float4(0.f, 0.f, 0.f, 0.f);
        } else if (kind == 1) {
            // ea f32 -> bf16 (one 16-wide edge row per thread)
            const int t = sub * 256 + threadIdx.x;
            const float4* src = (const float4*)(ea + (size_t)t * 16);
            const float4 a = src[0], bb = src[1], c = src[2], d = src[3];
            uint4 u0, u1;
            u0.x = pk2_hw(a.x, a.y);  u0.y = pk2_hw(a.z, a.w);
            u0.z = pk2_hw(bb.x, bb.y); u0.w = pk2_hw(bb.z, bb.w);
            u1.x = pk2_hw(c.x, c.y);  u1.y = pk2_hw(c.z, c.w);
            u1.z = pk2_hw(d.x, d.y);  u1.w = pk2_hw(d.z, d.w);
            uint4* dst = (uint4*)(eabf + (size_t)t * 16);
            dst[0] = u0; dst[1] = u1;
        } else {
            // count + rank in one atomic pass: returned old value IS the rank
            const int e = sub * 256 + threadIdx.x;
            rank[e] = atomicAdd(&counts[ei[e]], 1);
        }
        return;
    }
    const int idx = (b - TRI_BLOCKS) * 256 + threadIdx.x;
    if (idx < 10240) {                           // W1: K=160 padded (remapped)
        const int j = idx & 7, l = (idx >> 3) & 63, nt = (idx >> 9) & 3, c = idx >> 11;
        const int k = c * 32 + (l >> 4) * 8 + j, n = (l & 15) * 4 + nt;
        float wv = 0.0f;
        if (k < 129) wv = W1[k * 64 + n];                       // h,hc,logd
        else if (k >= 132 && k < 148) wv = W1[(k - 3) * 64 + n]; // ea rows
        W1p[idx] = (unsigned short)f2bf_hw(wv);
    } else if (idx < 14336) {                    // W2: K=64
        const int t = idx - 10240;
        const int j = t & 7, l = (t >> 3) & 63, nt = (t >> 9) & 3, c = t >> 11;
        W2p[t] = (unsigned short)f2bf_hw(W2[(c * 32 + (l >> 4) * 8 + j) * 64 + (l & 15) * 4 + nt]);
    } else if (idx < 18432) {                    // Wc1: K=64
        const int t = idx - 14336;
        const int j = t & 7, l = (t >> 3) & 63, nt = (t >> 9) & 3, c = t >> 11;
        Wc1p[t] = (unsigned short)f2bf_hw(Wc1[(c * 32 + (l >> 4) * 8 + j) * 64 + (l & 15) * 4 + nt]);
    } else if (idx < 26624) {                    // Wn1: K=128
        const int t = idx - 18432;
        const int j = t & 7, l = (t >> 3) & 63, nt = (t >> 9) & 3, c = t >> 11;
        Wn1p[t] = (unsigned short)f2bf_hw(Wn1[(c * 32 + (l >> 4) * 8 + j) * 64 + (l & 15) * 4 + nt]);
    } else if (idx < 30720) {                    // Wn2: K=64
        const int t = idx - 26624;
        const int j = t & 7, l = (t >> 3) & 63, nt = (t >> 9) & 3, c = t >> 11;
        Wn2p[t] = (unsigned short)f2bf_hw(Wn2[(c * 32 + (l >> 4) * 8 + j) * 64 + (l & 15) * 4 + nt]);
    }
}

// ---------------- CSR build (scan + fused atomic-free scatter) ----------------

#define SCAN_B 512
__global__ __launch_bounds__(SCAN_B) void scan1_kernel(const int* __restrict__ counts,
                                                       int* __restrict__ offs,
                                                       int* __restrict__ bsum) {
    __shared__ int s[SCAN_B];
    const int tid = threadIdx.x;
    const int idx = blockIdx.x * SCAN_B + tid;
    const int v = (idx < NN) ? counts[idx] : 0;
    s[tid] = v;
    __syncthreads();
    for (int off = 1; off < SCAN_B; off <<= 1) {
        const int t = (tid >= off) ? s[tid - off] : 0;
        __syncthreads();
        s[tid] += t;
        __syncthreads();
    }
    if (idx < NN) offs[idx] = s[tid] - v;         // block-local exclusive
    if (tid == SCAN_B - 1) bsum[blockIdx.x] = s[tid];
}

__global__ __launch_bounds__(SCAN_B) void scan2_kernel(int* __restrict__ bsum, int nblk) {
    __shared__ int s[SCAN_B];
    const int tid = threadIdx.x;
    const int v = (tid < nblk) ? bsum[tid] : 0;
    s[tid] = v;
    __syncthreads();
    for (int off = 1; off < SCAN_B; off <<= 1) {
        const int t = (tid >= off) ? s[tid - off] : 0;
        __syncthreads();
        s[tid] += t;
        __syncthreads();
    }
    if (tid < nblk) bsum[tid] = s[tid] - v;       // exclusive
}

// scatter with fused block-sum add (no scan3 pass)
__global__ void scatter_kernel(const int* __restrict__ ei, const int* __restrict__ offs,
                               const int* __restrict__ bsum, const int* __restrict__ rank,
                               int4* __restrict__ quads) {
    const int e = blockIdx.x * 256 + threadIdx.x;
    if (e >= NE) return;
    const int r = ei[e];
    const int c = ei[NE + e];
    const int pos = offs[r] + bsum[r >> 9] + rank[e];   // no atomic
    quads[pos] = make_int4(e, r, c, 0);
}

// ---------------- MFMA edge kernel with in-kernel segmented reductions -------
// 512 thr = 8 waves, 128 CSR-ordered edges/block, 16 edges/wave.
// BOTH reductions are wave-local; ONE barrier total (after staging).

#define FSTR 168   // bf16 row stride (160 + 8 pad; 336B)

__global__ __launch_bounds__(512, 6) void edge_mfma_kernel(
    const unsigned short* __restrict__ hbf, const float* __restrict__ x,
    const unsigned short* __restrict__ eabf,
    const unsigned short* __restrict__ W1p, const unsigned short* __restrict__ W2p,
    const unsigned short* __restrict__ Wc1p,
    const float* __restrict__ B1, const float* __restrict__ B2,
    const float* __restrict__ Bc1, const float* __restrict__ Wc2,
    const int4* __restrict__ quads,
    float* __restrict__ mf, float* __restrict__ xagg)
{
    __shared__ float sBias[256];        // B1 | B2 | Bc1 | Wc2
    __shared__ short sA[128 * FSTR];    // 43008 B
    __shared__ float sGeom[128 * 4];    // dx,dy,dz,dist
    __shared__ int   sRow[128];         // node id per slot
    __shared__ float sTrans[128][3];    // per-edge trans (wave-local use)

    const int tid = threadIdx.x;
    const int p0 = blockIdx.x * 128;

    if (tid < 64) {
        sBias[tid]       = B1[tid];
        sBias[64 + tid]  = B2[tid];
        sBias[128 + tid] = Bc1[tid];
        sBias[192 + tid] = Wc2[tid];
    }

    // stage features: 4 threads per edge slot
    {
        const int s = tid >> 2, q = tid & 3;
        const int4 pr = quads[p0 + s];
        const int eid = pr.x, row = pr.y, col = pr.z;

        const uint4* hr = (const uint4*)(hbf + (size_t)row * 64);
        *(uint4*)&sA[s * FSTR + q * 16]     = hr[q * 2];
        *(uint4*)&sA[s * FSTR + q * 16 + 8] = hr[q * 2 + 1];
        const uint4* hc = (const uint4*)(hbf + (size_t)col * 64);
        *(uint4*)&sA[s * FSTR + 64 + q * 16]     = hc[q * 2];
        *(uint4*)&sA[s * FSTR + 64 + q * 16 + 8] = hc[q * 2 + 1];

        // ea (pre-converted bf16): 4B-per... 8B per quadrant, 8B-aligned slots
        const uint2 e2 = *(const uint2*)(eabf + (size_t)eid * 16 + q * 4);
        *(uint2*)&sA[s * FSTR + 132 + q * 4] = e2;

        if (q == 0) {
            const float dx = x[row * 3 + 0] - x[col * 3 + 0];
            const float dy = x[row * 3 + 1] - x[col * 3 + 1];
            const float dz = x[row * 3 + 2] - x[col * 3 + 2];
            const float dist_sq = dx * dx + dy * dy + dz * dz;
            sGeom[s * 4 + 0] = dx;
            sGeom[s * 4 + 1] = dy;
            sGeom[s * 4 + 2] = dz;
            sGeom[s * 4 + 3] = sqrtf(dist_sq + EPS);
            sA[s * FSTR + 128] = f2bf_hw(log1pf(dist_sq));
        } else if (q == 1) {
            // zero pad k = 148..159
            *(uint4*)&sA[s * FSTR + 148] = make_uint4(0, 0, 0, 0);
            *(uint2*)&sA[s * FSTR + 156] = make_uint2(0, 0);
        } else if (q == 2) {
            sRow[s] = row;
        } else {
            // zero pad k = 129..131
            sA[s * FSTR + 129] = 0;
            sA[s * FSTR + 130] = 0;
            sA[s * FSTR + 131] = 0;
        }
    }
    __syncthreads();

    const int w = tid >> 6, l = tid & 63;
    const int lr = l & 15;
    const int ks = l >> 4;
    short* myA = &sA[(w * 16 + lr) * FSTR];

    // ---- msg layer 1: [16,160] @ [160,64], B via L1/L2 ----
    f32x4 acc[4];
    {
        const f32x4 b4 = *(const f32x4*)&sBias[lr * 4];
        #pragma unroll
        for (int nt = 0; nt < 4; ++nt)
            acc[nt] = (f32x4){b4[nt], b4[nt], b4[nt], b4[nt]};
    }
    #pragma unroll
    for (int c = 0; c < 5; ++c) {
        const bf16x8 af = *(const bf16x8*)&myA[c * 32 + ks * 8];
        #pragma unroll
        for (int nt = 0; nt < 4; ++nt) {
            const bf16x8 bf = *(const bf16x8*)&W1p[((c * 4 + nt) * 64 + l) * 8];
            acc[nt] = __builtin_amdgcn_mfma_f32_16x16x32_bf16(af, bf, acc[nt], 0, 0, 0);
        }
    }

    // prefetch W2 B-frags
    bf16x8 bw[8];
    #pragma unroll
    for (int c = 0; c < 2; ++c)
        #pragma unroll
        for (int nt = 0; nt < 4; ++nt)
            bw[c * 4 + nt] = *(const bf16x8*)&W2p[((c * 4 + nt) * 64 + l) * 8];

    {
        short* pw = &sA[(w * 16 + ks * 4) * FSTR + lr * 4];
        #pragma unroll
        for (int i = 0; i < 4; ++i) {
            uint2 u;
            u.x = pk2_hw(silu_f(acc[0][i]), silu_f(acc[1][i]));
            u.y = pk2_hw(silu_f(acc[2][i]), silu_f(acc[3][i]));
            *(uint2*)&pw[i * FSTR] = u;
        }
    }

    // ---- msg layer 2: [16,64] @ [64,64] ----
    f32x4 acc2[4];
    {
        const f32x4 b4 = *(const f32x4*)&sBias[64 + lr * 4];
        #pragma unroll
        for (int nt = 0; nt < 4; ++nt)
            acc2[nt] = (f32x4){b4[nt], b4[nt], b4[nt], b4[nt]};
    }
    #pragma unroll
    for (int c = 0; c < 2; ++c) {
        const bf16x8 af = *(const bf16x8*)&myA[c * 32 + ks * 8];
        #pragma unroll
        for (int nt = 0; nt < 4; ++nt)
            acc2[nt] = __builtin_amdgcn_mfma_f32_16x16x32_bf16(af, bw[c * 4 + nt], acc2[nt], 0, 0, 0);
    }

    // reload bw with Wc1 frags
    #pragma unroll
    for (int c = 0; c < 2; ++c)
        #pragma unroll
        for (int nt = 0; nt < 4; ++nt)
            bw[c * 4 + nt] = *(const bf16x8*)&Wc1p[((c * 4 + nt) * 64 + l) * 8];

    {
        short* pw = &sA[(w * 16 + ks * 4) * FSTR + lr * 4];
        #pragma unroll
        for (int i = 0; i < 4; ++i) {
            uint2 u;
            u.x = pk2_hw(silu_f(acc2[0][i]), silu_f(acc2[1][i]));
            u.y = pk2_hw(silu_f(acc2[2][i]), silu_f(acc2[3][i]));
            *(uint2*)&pw[i * FSTR] = u;
        }
    }

    // ---- coord layer 1: [16,64] @ [64,64], input = m (cols 0..63) ----
    f32x4 acc3[4];
    {
        const f32x4 b4 = *(const f32x4*)&sBias[128 + lr * 4];
        #pragma unroll
        for (int nt = 0; nt < 4; ++nt)
            acc3[nt] = (f32x4){b4[nt], b4[nt], b4[nt], b4[nt]};
    }
    #pragma unroll
    for (int c = 0; c < 2; ++c) {
        const bf16x8 af = *(const bf16x8*)&myA[c * 32 + ks * 8];
        #pragma unroll
        for (int nt = 0; nt < 4; ++nt)
            acc3[nt] = __builtin_amdgcn_mfma_f32_16x16x32_bf16(af, bw[c * 4 + nt], acc3[nt], 0, 0, 0);
    }
    float part[4] = {0.0f, 0.0f, 0.0f, 0.0f};
    {
        const f32x4 w4 = *(const f32x4*)&sBias[192 + lr * 4];
        #pragma unroll
        for (int nt = 0; nt < 4; ++nt) {
            #pragma unroll
            for (int i = 0; i < 4; ++i) part[i] += silu_f(acc3[nt][i]) * w4[nt];
        }
    }
    #pragma unroll
    for (int m = 1; m <= 8; m <<= 1) {
        #pragma unroll
        for (int i = 0; i < 4; ++i) part[i] += __shfl_xor(part[i], m, 64);
    }
    if (lr == 0) {
        #pragma unroll
        for (int i = 0; i < 4; ++i) {
            const int slot = w * 16 + ks * 4 + i;
            const float dist = sGeom[slot * 4 + 3];
            const float g2 = fminf(fmaxf(2.0f * part[i], -30.0f), 30.0f);
            const float t = __expf(g2);
            const float th = (t - 1.0f) * rcp_fast(t + 1.0f);
            const float sc = th * 0.1f * rcp_fast(dist + EPS);
            sTrans[slot][0] = sGeom[slot * 4 + 0] * sc;
            sTrans[slot][1] = sGeom[slot * 4 + 1] * sc;
            sTrans[slot][2] = sGeom[slot * 4 + 2] * sc;
        }
    }

    // ---- m segmented reduce: wave reduces its OWN 16 rows (uniform branches),
    //      coalesced f32 atomics (64 consecutive floats per burst) ----
    {
        const int baserow = w * 16;
        int run_node = sRow[baserow];
        float runsum = 0.0f;
        #pragma unroll
        for (int r = 0; r < 16; ++r) {
            const int n = sRow[baserow + r];
            const float v = bf2f((unsigned short)sA[(baserow + r) * FSTR + l]);
            if (n != run_node) {
                atomicAdd(&mf[(size_t)run_node * 64 + l], runsum);
                run_node = n;
                runsum = v;
            } else {
                runsum += v;
            }
        }
        atomicAdd(&mf[(size_t)run_node * 64 + l], runsum);
    }

    // ---- trans segmented reduce: wave-local walkers (no block barrier) ----
    __builtin_amdgcn_wave_barrier();
    asm volatile("s_waitcnt lgkmcnt(0)");
    __builtin_amdgcn_sched_barrier(0);
    if (l < 16) {
        const int s = w * 16 + l;
        const int n = sRow[s];
        if (l == 0 || sRow[s - 1] != n) {
            float sx = 0.0f, sy = 0.0f, sz = 0.0f;
            int j = s;
            const int jend = w * 16 + 16;
            while (j < jend && sRow[j] == n) {
                sx += sTrans[j][0];
                sy += sTrans[j][1];
                sz += sTrans[j][2];
                ++j;
            }
            atomicAdd(&xagg[n * 4 + 0], sx);
            atomicAdd(&xagg[n * 4 + 1], sy);
            atomicAdd(&xagg[n * 4 + 2], sz);
        }
    }
}

// ---------------- MFMA node kernel: MLP + residual + LayerNorm + x finalize --

#define NSTR 136   // 128 + 8 pad

__global__ __launch_bounds__(256) void node_mfma_kernel(
    const unsigned short* __restrict__ hbf, const float* __restrict__ mf,
    const int* __restrict__ counts,
    const unsigned short* __restrict__ Wn1p, const unsigned short* __restrict__ Wn2p,
    const float* __restrict__ Bn1, const float* __restrict__ Bn2,
    const float* __restrict__ ln_g, const float* __restrict__ ln_b,
    const float* __restrict__ x, const float* __restrict__ xagg,
    float* __restrict__ h_out, float* __restrict__ x_out)
{
    __shared__ short sA[64 * NSTR];   // 17408 B
    __shared__ float sBias[256];      // Bn1 | Bn2 | g | b

    const int tid = threadIdx.x;
    const int n0 = blockIdx.x * 64;

    if (tid < 64) {
        sBias[tid]       = Bn1[tid];
        sBias[64 + tid]  = Bn2[tid];
        sBias[128 + tid] = ln_g[tid];
        sBias[192 + tid] = ln_b[tid];
    }
    {
        const int s = tid >> 2, q = tid & 3;
        const int node = n0 + s;
        const int n = (node < NN) ? node : (NN - 1);
        const uint4* hr = (const uint4*)(hbf + (size_t)n * 64);
        *(uint4*)&sA[s * NSTR + q * 16]     = hr[q * 2];
        *(uint4*)&sA[s * NSTR + q * 16 + 8] = hr[q * 2 + 1];
        // m_i = mf / (count + EPS), f32 -> bf16
        const float inv = rcp_fast((float)counts[n] + EPS);
        const float4* mr = (const float4*)(mf + (size_t)n * 64) + q * 4;
        #pragma unroll
        for (int c2 = 0; c2 < 2; ++c2) {
            const float4 a = mr[c2 * 2], b = mr[c2 * 2 + 1];
            uint4 u;
            u.x = pk2_hw(a.x * inv, a.y * inv); u.y = pk2_hw(a.z * inv, a.w * inv);
            u.z = pk2_hw(b.x * inv, b.y * inv); u.w = pk2_hw(b.z * inv, b.w * inv);
            *(uint4*)&sA[s * NSTR + 64 + q * 16 + c2 * 8] = u;
        }
    }
    __syncthreads();

    const int w = tid >> 6, l = tid & 63;
    const int lr = l & 15;
    const int ks = l >> 4;
    const short* myA = &sA[(w * 16 + lr) * NSTR];

    // ---- node layer 1: [16,128] @ [128,64] ----
    f32x4 acc[4];
    {
        const f32x4 b4 = *(const f32x4*)&sBias[lr * 4];
        #pragma unroll
        for (int nt = 0; nt < 4; ++nt)
            acc[nt] = (f32x4){b4[nt], b4[nt], b4[nt], b4[nt]};
    }
    #pragma unroll
    for (int c = 0; c < 4; ++c) {
        const bf16x8 af = *(const bf16x8*)&myA[c * 32 + ks * 8];
        #pragma unroll
        for (int nt = 0; nt < 4; ++nt) {
            const bf16x8 bf = *(const bf16x8*)&Wn1p[((c * 4 + nt) * 64 + l) * 8];
            acc[nt] = __builtin_amdgcn_mfma_f32_16x16x32_bf16(af, bf, acc[nt], 0, 0, 0);
        }
    }
    // silu -> cols 64..127 (channel-perm packed writes)
    {
        short* pw = &sA[(w * 16 + ks * 4) * NSTR + 64 + lr * 4];
        #pragma unroll
        for (int i = 0; i < 4; ++i) {
            uint2 u;
            u.x = pk2_hw(silu_f(acc[0][i]), silu_f(acc[1][i]));
            u.y = pk2_hw(silu_f(acc[2][i]), silu_f(acc[3][i]));
            *(uint2*)&pw[i * NSTR] = u;
        }
    }

    // ---- node layer 2: [16,64] @ [64,64] ----
    f32x4 acc2[4];
    {
        const f32x4 b4 = *(const f32x4*)&sBias[64 + lr * 4];
        #pragma unroll
        for (int nt = 0; nt < 4; ++nt)
            acc2[nt] = (f32x4){b4[nt], b4[nt], b4[nt], b4[nt]};
    }
    #pragma unroll
    for (int c = 0; c < 2; ++c) {
        const bf16x8 af = *(const bf16x8*)&myA[64 + c * 32 + ks * 8];
        #pragma unroll
        for (int nt = 0; nt < 4; ++nt) {
            const bf16x8 bf = *(const bf16x8*)&Wn2p[((c * 4 + nt) * 64 + l) * 8];
            acc2[nt] = __builtin_amdgcn_mfma_f32_16x16x32_bf16(af, bf, acc2[nt], 0, 0, 0);
        }
    }

    // residual: thread's 4 nt channels are contiguous (lr*4..+3) -> b64 read
    float a2[4][4];
    #pragma unroll
    for (int i = 0; i < 4; ++i) {
        const uint2 hres = *(const uint2*)&sA[(w * 16 + ks * 4 + i) * NSTR + lr * 4];
        a2[0][i] = acc2[0][i] + bf2f((unsigned short)(hres.x & 0xffffu));
        a2[1][i] = acc2[1][i] + bf2f((unsigned short)(hres.x >> 16));
        a2[2][i] = acc2[2][i] + bf2f((unsigned short)(hres.y & 0xffffu));
        a2[3][i] = acc2[3][i] + bf2f((unsigned short)(hres.y >> 16));
    }

    float su[4];
    #pragma unroll
    for (int i = 0; i < 4; ++i)
        su[i] = a2[0][i] + a2[1][i] + a2[2][i] + a2[3][i];
    #pragma unroll
    for (int m = 1; m <= 8; m <<= 1)
        #pragma unroll
        for (int i = 0; i < 4; ++i) su[i] += __shfl_xor(su[i], m, 64);
    float mu[4];
    #pragma unroll
    for (int i = 0; i < 4; ++i) mu[i] = su[i] * (1.0f / 64.0f);

    float sv[4];
    #pragma unroll
    for (int i = 0; i < 4; ++i) {
        float s = 0.0f;
        #pragma unroll
        for (int nt = 0; nt < 4; ++nt) {
            const float d = a2[nt][i] - mu[i];
            s += d * d;
        }
        sv[i] = s;
    }
    #pragma unroll
    for (int m = 1; m <= 8; m <<= 1)
        #pragma unroll
        for (int i = 0; i < 4; ++i) sv[i] += __shfl_xor(sv[i], m, 64);

    {
        const f32x4 g4 = *(const f32x4*)&sBias[128 + lr * 4];
        const f32x4 b4 = *(const f32x4*)&sBias[192 + lr * 4];
        #pragma unroll
        for (int i = 0; i < 4; ++i) {
            const float rstd = rsqrtf(sv[i] * (1.0f / 64.0f) + LN_EPS);
            const int node = n0 + w * 16 + ks * 4 + i;
            if (node < NN) {
                float4 o;
                o.x = (a2[0][i] - mu[i]) * rstd * g4[0] + b4[0];
                o.y = (a2[1][i] - mu[i]) * rstd * g4[1] + b4[1];
                o.z = (a2[2][i] - mu[i]) * rstd * g4[2] + b4[2];
                o.w = (a2[3][i] - mu[i]) * rstd * g4[3] + b4[3];
                *(float4*)&h_out[(size_t)node * 64 + lr * 4] = o;
            }
        }
    }

    // ---- fused x finalize: one thread per node ----
    if (tid < 64) {
        const int n = n0 + tid;
        if (n < NN) {
            const float inv = rcp_fast((float)counts[n] + EPS);
            x_out[(size_t)n * 3 + 0] = x[(size_t)n * 3 + 0] + xagg[n * 4 + 0] * inv;
            x_out[(size_t)n * 3 + 1] = x[(size_t)n * 3 + 1] + xagg[n * 4 + 1] * inv;
            x_out[(size_t)n * 3 + 2] = x[(size_t)n * 3 + 2] + xagg[n * 4 + 2] * inv;
        }
    }
}

// ---------------- fallback (atomic path, minimal ws) ----------------

__global__ __launch_bounds__(64) void edge_atomic_kernel(
    const float* __restrict__ h, const float* __restrict__ x,
    const int* __restrict__ ei, const float* __restrict__ ea,
    const float* __restrict__ W1, const float* __restrict__ B1,
    const float* __restrict__ W2, const float* __restrict__ B2,
    const float* __restrict__ Wc1, const float* __restrict__ Bc1,
    const float* __restrict__ Wc2,
    float* __restrict__ m_acc, float* __restrict__ xagg)
{
    __shared__ float lds[64 * 64];
    const int lane = threadIdx.x;
    const int e = blockIdx.x * 64 + lane;

    const int row = ei[e];
    const int col = ei[NE + e];

    const float dx = x[row * 3 + 0] - x[col * 3 + 0];
    const float dy = x[row * 3 + 1] - x[col * 3 + 1];
    const float dz = x[row * 3 + 2] - x[col * 3 + 2];
    const float dist_sq = dx * dx + dy * dy + dz * dz;
    const float dist = sqrtf(dist_sq + EPS);
    const float logd = log1pf(dist_sq);

    float a1[64];
    #pragma unroll
    for (int j = 0; j < 64; ++j) a1[j] = B1[j];
    const float4* hr4 = (const float4*)(h + (size_t)row * 64);
    for (int k4 = 0; k4 < 16; ++k4) {
        const float4 v4 = hr4[k4];
        #pragma unroll
        for (int c = 0; c < 4; ++c) {
            const float v = (c == 0) ? v4.x : (c == 1) ? v4.y : (c == 2) ? v4.z : v4.w;
            const float* w = W1 + (k4 * 4 + c) * 64;
            #pragma unroll
            for (int j = 0; j < 64; ++j) a1[j] = fmaf(v, w[j], a1[j]);
        }
    }
    const float4* hc4 = (const float4*)(h + (size_t)col * 64);
    for (int k4 = 0; k4 < 16; ++k4) {
        const float4 v4 = hc4[k4];
        #pragma unroll
        for (int c = 0; c < 4; ++c) {
            const float v = (c == 0) ? v4.x : (c == 1) ? v4.y : (c == 2) ? v4.z : v4.w;
            const float* w = W1 + (64 + k4 * 4 + c) * 64;
            #pragma unroll
            for (int j = 0; j < 64; ++j) a1[j] = fmaf(v, w[j], a1[j]);
        }
    }
    {
        const float* w = W1 + 128 * 64;
        #pragma unroll
        for (int j = 0; j < 64; ++j) a1[j] = fmaf(logd, w[j], a1[j]);
    }
    const float4* ea4 = (const float4*)(ea + (size_t)e * 16);
    for (int k4 = 0; k4 < 4; ++k4) {
        const float4 v4 = ea4[k4];
        #pragma unroll
        for (int c = 0; c < 4; ++c) {
            const float v = (c == 0) ? v4.x : (c == 1) ? v4.y : (c == 2) ? v4.z : v4.w;
            const float* w = W1 + (129 + k4 * 4 + c) * 64;
            #pragma unroll
            for (int j = 0; j < 64; ++j) a1[j] = fmaf(v, w[j], a1[j]);
        }
    }

    #pragma unroll
    for (int j = 0; j < 64; ++j) lds[j * 64 + lane] = silu_f(a1[j]);

    float a2[64];
    #pragma unroll
    for (int j = 0; j < 64; ++j) a2[j] = B2[j];
    for (int k = 0; k < 64; ++k) {
        const float v = lds[k * 64 + lane];
        const float* w = W2 + k * 64;
        #pragma unroll
        for (int j = 0; j < 64; ++j) a2[j] = fmaf(v, w[j], a2[j]);
    }

    float* mrow = m_acc + (size_t)row * 64;
    #pragma unroll
    for (int j = 0; j < 64; ++j) {
        const float mj = silu_f(a2[j]);
        lds[j * 64 + lane] = mj;
        atomicAdd(mrow + j, mj);
    }

    float t[64];
    #pragma unroll
    for (int j = 0; j < 64; ++j) t[j] = Bc1[j];
    for (int k = 0; k < 64; ++k) {
        const float v = lds[k * 64 + lane];
        const float* w = Wc1 + k * 64;
        #pragma unroll
        for (int j = 0; j < 64; ++j) t[j] = fmaf(v, w[j], t[j]);
    }
    float g = 0.0f;
    #pragma unroll
    for (int j = 0; j < 64; ++j) g += silu_f(t[j]) * Wc2[j];

    const float s = tanhf(g) * 0.1f / (dist + EPS);
    atomicAdd(&xagg[row * 4 + 0], dx * s);
    atomicAdd(&xagg[row * 4 + 1], dy * s);
    atomicAdd(&xagg[row * 4 + 2], dz * s);
    atomicAdd(&xagg[row * 4 + 3], 1.0f);
}

__global__ __launch_bounds__(64) void node_csr_kernel(
    const float* __restrict__ h,
    const float* __restrict__ m_i,
    const float* __restrict__ Wn1, const float* __restrict__ Bn1,
    const float* __restrict__ Wn2, const float* __restrict__ Bn2,
    const float* __restrict__ ln_g, const float* __restrict__ ln_b,
    float* __restrict__ h_out)
{
    __shared__ float lds[64 * 64];
    const int lane = threadIdx.x;
    const int node = blockIdx.x * 64 + lane;
    const bool act = node < NN;
    const int n = act ? node : 0;

    float a1[64];
    #pragma unroll
    for (int j = 0; j < 64; ++j) a1[j] = Bn1[j];

    const float* hr = h + (size_t)n * 64;
    const float4* hr4 = (const float4*)hr;
    for (int k4 = 0; k4 < 16; ++k4) {
        const float4 v4 = hr4[k4];
        #pragma unroll
        for (int c = 0; c < 4; ++c) {
            const float v = (c == 0) ? v4.x : (c == 1) ? v4.y : (c == 2) ? v4.z : v4.w;
            const float* w = Wn1 + (k4 * 4 + c) * 64;
            #pragma unroll
            for (int j = 0; j < 64; ++j) a1[j] = fmaf(v, w[j], a1[j]);
        }
    }
    const float4* mr4 = (const float4*)(m_i + (size_t)n * 64);
    for (int k4 = 0; k4 < 16; ++k4) {
        const float4 v4 = mr4[k4];
        #pragma unroll
        for (int c = 0; c < 4; ++c) {
            const float v = (c == 0) ? v4.x : (c == 1) ? v4.y : (c == 2) ? v4.z : v4.w;
            const float* w = Wn1 + (64 + k4 * 4 + c) * 64;
            #pragma unroll
            for (int j = 0; j < 64; ++j) a1[j] = fmaf(v, w[j], a1[j]);
        }
    }

    #pragma unroll
    for (int j = 0; j < 64; ++j) lds[j * 64 + lane] = silu_f(a1[j]);

    float a2[64];
    #pragma unroll
    for (int j = 0; j < 64; ++j) a2[j] = Bn2[j];
    for (int k = 0; k < 64; ++k) {
        const float v = lds[k * 64 + lane];
        const float* w = Wn2 + k * 64;
        #pragma unroll
        for (int j = 0; j < 64; ++j) a2[j] = fmaf(v, w[j], a2[j]);
    }

    float mu = 0.0f;
    #pragma unroll
    for (int j = 0; j < 64; ++j) { a2[j] += hr[j]; mu += a2[j]; }
    mu *= (1.0f / 64.0f);
    float var = 0.0f;
    #pragma unroll
    for (int j = 0; j < 64; ++j) { const float d = a2[j] - mu; var += d * d; }
    var *= (1.0f / 64.0f);
    const float rstd = rsqrtf(var + LN_EPS);

    if (act) {
        #pragma unroll
        for (int j = 0; j < 64; ++j)
            h_out[(size_t)n * 64 + j] = (a2[j] - mu) * rstd * ln_g[j] + ln_b[j];
    }
}

__global__ void x_atomic_kernel(const float* __restrict__ x, const float* __restrict__ xagg,
                                float* __restrict__ x_out)
{
    const int i = blockIdx.x * 256 + threadIdx.x;
    if (i >= NN) return;
    const float inv_cnt = 1.0f / (xagg[i * 4 + 3] + EPS);
    #pragma unroll
    for (int c = 0; c < 3; ++c)
        x_out[(size_t)i * 3 + c] = x[(size_t)i * 3 + c] + xagg[i * 4 + c] * inv_cnt;
}

__global__ void div_m_kernel(float* __restrict__ m_acc, const float* __restrict__ xagg) {
    const int i = blockIdx.x * 256 + threadIdx.x;
    if (i >= NN * 64) return;
    m_acc[i] /= (xagg[(i >> 6) * 4 + 3] + EPS);
}

// ---------------- launch ----------------

extern "C" void kernel_launch(void* const* d_in, const int* in_sizes, int n_in,
                              void* d_out, int out_size, void* d_ws, size_t ws_size,
                              hipStream_t stream)
{
    const float* h   = (const float*)d_in[0];
    const float* x   = (const float*)d_in[1];
    const int*   ei  = (const int*)d_in[2];
    const float* ea  = (const float*)d_in[3];
    const float* W1  = (const float*)d_in[4];
    const float* B1  = (const float*)d_in[5];
    const float* W2  = (const float*)d_in[6];
    const float* B2  = (const float*)d_in[7];
    const float* Wn1 = (const float*)d_in[8];
    const float* Bn1 = (const float*)d_in[9];
    const float* Wn2 = (const float*)d_in[10];
    const float* Bn2 = (const float*)d_in[11];
    const float* Wc1 = (const float*)d_in[12];
    const float* Bc1 = (const float*)d_in[13];
    const float* Wc2 = (const float*)d_in[14];
    const float* lng = (const float*)d_in[15];
    const float* lnb = (const float*)d_in[16];

    float* out   = (float*)d_out;
    float* x_out = out + (size_t)NN * 64;

    size_t off = 0;
    auto take = [&](size_t bytes) { size_t p = off; off = (off + bytes + 255) & ~(size_t)255; return p; };
    char* ws = (char*)d_ws;
    const size_t o_quads  = take((size_t)NE * 16);         // int4 {eid,row,col,-}
    const size_t o_counts = take((size_t)NN * 4);
    const size_t o_rank   = take((size_t)NE * 4);          // within-node rank per edge
    const size_t o_offs   = take((size_t)(NN + 1) * 4);
    const size_t o_bsum   = take((size_t)1024 * 4);
    const size_t o_hbf    = take((size_t)NN * 64 * 2);     // bf16 h
    const size_t o_eabf   = take((size_t)NE * 16 * 2);     // bf16 ea
    const size_t o_mf     = take((size_t)NN * 64 * 4);     // f32 m sum accumulator
    const size_t o_xagg   = take((size_t)NN * 4 * 4);      // f32 x aggregate
    const size_t o_w1p    = take((size_t)10240 * 2);
    const size_t o_w2p    = take((size_t)4096 * 2);
    const size_t o_wc1p   = take((size_t)4096 * 2);
    const size_t o_wn1p   = take((size_t)8192 * 2);
    const size_t o_wn2p   = take((size_t)4096 * 2);
    const size_t need = off;

    if (ws_size >= need) {
        int4*  quads  = (int4*)(ws + o_quads);
        int*   counts = (int*)(ws + o_counts);
        int*   rank   = (int*)(ws + o_rank);
        int*   offs   = (int*)(ws + o_offs);
        int*   bsum   = (int*)(ws + o_bsum);
        unsigned short* hbf   = (unsigned short*)(ws + o_hbf);
        unsigned short* eabf  = (unsigned short*)(ws + o_eabf);
        float* mf     = (float*)(ws + o_mf);
        float* xagg   = (float*)(ws + o_xagg);
        unsigned short* W1p   = (unsigned short*)(ws + o_w1p);
        unsigned short* W2p   = (unsigned short*)(ws + o_w2p);
        unsigned short* Wc1p  = (unsigned short*)(ws + o_wc1p);
        unsigned short* Wn1p  = (unsigned short*)(ws + o_wn1p);
        unsigned short* Wn2p  = (unsigned short*)(ws + o_wn2p);

        hipMemsetAsync(counts, 0, (size_t)NN * 4, stream);
        hipMemsetAsync(xagg, 0, (size_t)NN * 4 * 4, stream);
        // mf zeroed inside prep_count_kernel's h-blocks (no separate memset)

        prep_count_kernel<<<TRI_BLOCKS + PW_BLOCKS, 256, 0, stream>>>(
            h, ea, W1, W2, Wc1, Wn1, Wn2, ei,
            hbf, eabf, W1p, W2p, Wc1p, Wn1p, Wn2p, counts, rank, mf);

        const int nblk = (NN + SCAN_B - 1) / SCAN_B;
        scan1_kernel<<<nblk, SCAN_B, 0, stream>>>(counts, offs, bsum);
        scan2_kernel<<<1, SCAN_B, 0, stream>>>(bsum, nblk);
        scatter_kernel<<<(NE + 255) / 256, 256, 0, stream>>>(ei, offs, bsum, rank, quads);

        edge_mfma_kernel<<<NE / 128, 512, 0, stream>>>(hbf, x, eabf, W1p, W2p, Wc1p,
                                                       B1, B2, Bc1, Wc2, quads,
                                                       mf, xagg);
        node_mfma_kernel<<<(NN + 63) / 64, 256, 0, stream>>>(hbf, mf, counts, Wn1p, Wn2p,
                                                             Bn1, Bn2, lng, lnb,
                                                             x, xagg, out, x_out);
    } else {
        float* m_acc = out;
        float* xagg  = (float*)d_ws;
        hipMemsetAsync(m_acc, 0, (size_t)NN * 64 * 4, stream);
        hipMemsetAsync(xagg, 0, (size_t)NN * 4 * 4, stream);
        edge_atomic_kernel<<<NE / 64, 64, 0, stream>>>(h, x, ei, ea, W1, B1, W2, B2,
                                                       Wc1, Bc1, Wc2, m_acc, xagg);
        div_m_kernel<<<(NN * 64 + 255) / 256, 256, 0, stream>>>(m_acc, xagg);
        node_csr_kernel<<<(NN + 63) / 64, 64, 0, stream>>>(h, m_acc, Wn1, Bn1, Wn2, Bn2,
                                                           lng, lnb, m_acc);
        x_atomic_kernel<<<(NN + 255) / 256, 256, 0, stream>>>(x, xagg, m_acc + (size_t)NN * 64);
    }
}